// Round 16
// baseline (191.403 us; speedup 1.0000x reference)
//
#include <hip/hip_runtime.h>
#include <hip/hip_bf16.h>

#define S_LEN 4096
#define D_EMB 768
#define NH    12
#define HD    64
#define DQKV  2304
#define DFF   3072

typedef __attribute__((ext_vector_type(4))) short short4v;
typedef __attribute__((ext_vector_type(8))) short short8v;
typedef __attribute__((ext_vector_type(4))) float float4v;

static __device__ __forceinline__ float4v mfma16(short4v a, short4v b, float4v c) {
  return __builtin_amdgcn_mfma_f32_16x16x16bf16_1k(a, b, c, 0, 0, 0);
}

static __device__ __forceinline__ short bf16bits(float f) {
  __hip_bfloat16 h = __float2bfloat16(f);
  return *reinterpret_cast<short*>(&h);
}

static __device__ __forceinline__ float fast_exp2(float x) {
#if __has_builtin(__builtin_amdgcn_exp2f)
  return __builtin_amdgcn_exp2f(x);   // bare v_exp_f32
#else
  return exp2f(x);
#endif
}

// async global -> LDS, 16B per lane. LDS dest must be wave-uniform base + lane*16.
static __device__ __forceinline__ void gload16(const __hip_bfloat16* g, __hip_bfloat16* l) {
  __builtin_amdgcn_global_load_lds((const __attribute__((address_space(1))) void*)g,
                                   (__attribute__((address_space(3))) void*)l, 16, 0, 0);
}

// ---------------- LayerNorm: fp32 in -> bf16 out, one block per row ----------------
__global__ __launch_bounds__(256) void ln_kernel(const float* __restrict__ x,
    const float* __restrict__ g, const float* __restrict__ b,
    __hip_bfloat16* __restrict__ out)
{
  int row = blockIdx.x;
  int tid = threadIdx.x;
  const float* xr = x + (size_t)row * D_EMB;
  float v0 = xr[tid], v1 = xr[tid + 256], v2 = xr[tid + 512];
  float s  = v0 + v1 + v2;
  float sq = v0 * v0 + v1 * v1 + v2 * v2;
  #pragma unroll
  for (int off = 32; off >= 1; off >>= 1) {
    s  += __shfl_xor(s, off);
    sq += __shfl_xor(sq, off);
  }
  __shared__ float ss[4], ssq[4];
  if ((tid & 63) == 0) { ss[tid >> 6] = s; ssq[tid >> 6] = sq; }
  __syncthreads();
  s  = ss[0] + ss[1] + ss[2] + ss[3];
  sq = ssq[0] + ssq[1] + ssq[2] + ssq[3];
  float mean = s * (1.0f / D_EMB);
  float var  = sq * (1.0f / D_EMB) - mean * mean;
  float rstd = rsqrtf(var + 1e-5f);
  __hip_bfloat16* orow = out + (size_t)row * D_EMB;
  orow[tid]       = __float2bfloat16((v0 - mean) * rstd * g[tid]       + b[tid]);
  orow[tid + 256] = __float2bfloat16((v1 - mean) * rstd * g[tid + 256] + b[tid + 256]);
  orow[tid + 512] = __float2bfloat16((v2 - mean) * rstd * g[tid + 512] + b[tid + 512]);
}

// ---------------- merged weight transposes: fp32 [K][N] -> bf16 [N][K] ----------------
__global__ __launch_bounds__(256) void transpose_all_kernel(
    const float* __restrict__ w_qkv, const float* __restrict__ w_proj,
    const float* __restrict__ w_fc1, const float* __restrict__ w_fc2,
    __hip_bfloat16* __restrict__ wqkvT, __hip_bfloat16* __restrict__ wprojT,
    __hip_bfloat16* __restrict__ wfc1T, __hip_bfloat16* __restrict__ wfc2T)
{
  __shared__ float t[32][33];
  int bid = blockIdx.x;
  const float* in; __hip_bfloat16* out; int K, N, tt;
  if (bid < 1728)      { in = w_qkv;  out = wqkvT;  K = D_EMB; N = DQKV;  tt = bid; }
  else if (bid < 2304) { in = w_proj; out = wprojT; K = D_EMB; N = D_EMB; tt = bid - 1728; }
  else if (bid < 4608) { in = w_fc1;  out = wfc1T;  K = D_EMB; N = DFF;   tt = bid - 2304; }
  else                 { in = w_fc2;  out = wfc2T;  K = DFF;   N = D_EMB; tt = bid - 4608; }
  int nb = N >> 5;
  int bn = tt % nb, bk = tt / nb;
  int tx = threadIdx.x & 31, ty = threadIdx.x >> 5;
  #pragma unroll
  for (int i = 0; i < 4; i++)
    t[ty + 8 * i][tx] = in[(size_t)(bk * 32 + ty + 8 * i) * N + bn * 32 + tx];
  __syncthreads();
  #pragma unroll
  for (int i = 0; i < 4; i++)
    out[(size_t)(bn * 32 + ty + 8 * i) * K + bk * 32 + tx] = __float2bfloat16(t[tx][ty + 8 * i]);
}

// ---------------- GEMM v3: BK=32 double-buffered one-barrier loop (32KB LDS) ----------------
// Stage half-slab t+1 issued AFTER the barrier, drained at the NEXT barrier -> a full
// 16-MFMA compute phase of latency slack, same LDS/barrier budget as single-buffer.
// Read chunk ch = lg ^ ((li>>1)&3) (<=2-way banks); source chunk inverse = same XOR.
// EPI 0: +bias -> bf16   EPI 1: +bias, tanh-GELU -> bf16   EPI 2: +bias +resid -> fp32
// EPI 3: bf16 partial to Cout + split*M*N (no bias)
// EPI 4: +bias -> bf16, V-region cols (>=2*D_EMB) also scattered to vtout[d][s]
template<int EPI>
__global__ __launch_bounds__(256) void gemm_kernel(
    const __hip_bfloat16* __restrict__ A,
    const __hip_bfloat16* __restrict__ Bt,
    const float* __restrict__ bias,
    const float* __restrict__ resid,
    void* __restrict__ Cout,
    __hip_bfloat16* __restrict__ vtout,
    int M, int N, int Kfull, int kChunk)
{
  __shared__ __hip_bfloat16 Asm[2][128 * 32];
  __shared__ __hip_bfloat16 Bsm[2][128 * 32];
  int nb = N >> 7, mb = M >> 7;
  int tilesPer = nb * mb;
  int split = blockIdx.x / tilesPer;
  int b2 = blockIdx.x % tilesPer;
  int bx = b2 % nb, by = b2 / nb;
  int m0 = by << 7, n0 = bx << 7;
  int k0 = split * kChunk;
  int tid = threadIdx.x;
  int lane = tid & 63, lg = lane >> 4, li = lane & 15;
  int w = tid >> 6, wr = w >> 1, wc = w & 1;

  // staging roles: row sr = tid>>2 (0..63; +64 second issue), source chunk swizzled
  int sr  = tid >> 2;
  int scn = (tid & 3) ^ ((tid >> 3) & 3);
  const __hip_bfloat16* aSrc = A  + (size_t)(m0 + sr) * Kfull + k0 + scn * 8;
  const __hip_bfloat16* bSrc = Bt + (size_t)(n0 + sr) * Kfull + k0 + scn * 8;
  const size_t rowStep = (size_t)64 * Kfull;

  float4v acc[4][4];
  #pragma unroll
  for (int i = 0; i < 4; i++)
    #pragma unroll
    for (int j = 0; j < 4; j++) {
      float4v z = {0.f, 0.f, 0.f, 0.f};
      acc[i][j] = z;
    }

  int ch = lg ^ ((li >> 1) & 3);    // read chunk within 32-wide row
  int nk = kChunk >> 5;

  // prologue: stage slab 0 into buffer 0
  gload16(aSrc,           Asm[0] + tid * 8);
  gload16(aSrc + rowStep, Asm[0] + tid * 8 + 2048);
  gload16(bSrc,           Bsm[0] + tid * 8);
  gload16(bSrc + rowStep, Bsm[0] + tid * 8 + 2048);
  aSrc += 32; bSrc += 32;

  for (int t = 0; t < nk; ++t) {
    int p = t & 1;
    __syncthreads();        // drains vmcnt: buf[p] staged; all waves done reading buf[p^1]
    if (t + 1 < nk) {       // stage next slab; drains at NEXT barrier (full compute of slack)
      gload16(aSrc,           Asm[p ^ 1] + tid * 8);
      gload16(aSrc + rowStep, Asm[p ^ 1] + tid * 8 + 2048);
      gload16(bSrc,           Bsm[p ^ 1] + tid * 8);
      gload16(bSrc + rowStep, Bsm[p ^ 1] + tid * 8 + 2048);
      aSrc += 32; bSrc += 32;
    }
    short8v af[4], bf[4];
    #pragma unroll
    for (int f = 0; f < 4; f++) {
      af[f] = *(const short8v*)(Asm[p] + (wr * 64 + f * 16 + li) * 32 + ch * 8);
      bf[f] = *(const short8v*)(Bsm[p] + (wc * 64 + f * 16 + li) * 32 + ch * 8);
    }
    #pragma unroll
    for (int fr = 0; fr < 4; fr++)
      #pragma unroll
      for (int fc = 0; fc < 4; fc++)
        acc[fr][fc] = __builtin_amdgcn_mfma_f32_16x16x32_bf16(af[fr], bf[fc], acc[fr][fc], 0, 0, 0);
  }

  #pragma unroll
  for (int fr = 0; fr < 4; fr++) {
    int row = m0 + wr * 64 + fr * 16 + lg * 4;
    #pragma unroll
    for (int fc = 0; fc < 4; fc++) {
      int col = n0 + wc * 64 + fc * 16 + li;
      float bv = (EPI == 3) ? 0.f : bias[col];
      short4v tv;
      #pragma unroll
      for (int r = 0; r < 4; r++) {
        float v = acc[fr][fc][r] + bv;
        size_t idx = (size_t)(row + r) * N + col;
        if (EPI == 1) {
          // GELU(v) ~= v * sigmoid(2u), u = 0.79788456(v + 0.044715 v^3)
          float u = 0.7978845608028654f * (v + 0.044715f * v * v * v);
          float e = fast_exp2(u * 2.8853900817779268f);   // exp(2u)
#if __has_builtin(__builtin_amdgcn_rcpf)
          float r1 = __builtin_amdgcn_rcpf(e + 1.0f);
#else
          float r1 = 1.0f / (e + 1.0f);
#endif
          v = v * e * r1;
          ((__hip_bfloat16*)Cout)[idx] = __float2bfloat16(v);
        } else if (EPI == 2) {
          ((float*)Cout)[idx] = v + resid[idx];
        } else if (EPI == 3) {
          ((__hip_bfloat16*)Cout)[(size_t)split * M * N + idx] = __float2bfloat16(v);
        } else {
          __hip_bfloat16 hb = __float2bfloat16(v);
          ((__hip_bfloat16*)Cout)[idx] = hb;
          if (EPI == 4) tv[r] = *reinterpret_cast<short*>(&hb);
        }
      }
      if (EPI == 4 && col >= 2 * D_EMB) {
        *reinterpret_cast<short4v*>(vtout + (size_t)(col - 2 * D_EMB) * S_LEN + row) = tv;
      }
    }
  }
}

// ---------------- split-K reduce (bf16 parts): out = resid + bias + sum(parts) ----------------
template<int NS>
__global__ __launch_bounds__(256) void reduce_kernel(const __hip_bfloat16* __restrict__ parts,
    const float* __restrict__ bias, const float* __restrict__ resid,
    float* __restrict__ out, int n4)
{
  const size_t MN = (size_t)S_LEN * D_EMB;
  int stride = gridDim.x * 256;
  for (int e = blockIdx.x * 256 + threadIdx.x; e < n4; e += stride) {
    float4v acc = *(const float4v*)(resid + 4 * (size_t)e);
    int col = (e * 4) % D_EMB;
    float4v bv = *(const float4v*)(bias + col);
    acc += bv;
    #pragma unroll
    for (int s = 0; s < NS; s++) {
      short4v pv = *(const short4v*)(parts + (size_t)s * MN + 4 * (size_t)e);
      #pragma unroll
      for (int j = 0; j < 4; j++) {
        unsigned int u = ((unsigned int)(unsigned short)pv[j]) << 16;
        acc[j] += *reinterpret_cast<float*>(&u);
      }
    }
    *(float4v*)(out + 4 * (size_t)e) = acc;
  }
}

// ---------------- fused split-K(3, bf16) reduce + LayerNorm ----------------
__global__ __launch_bounds__(256) void reduce_ln_kernel(const __hip_bfloat16* __restrict__ parts,
    const float* __restrict__ bias, const float* __restrict__ resid,
    const float* __restrict__ g, const float* __restrict__ b,
    float* __restrict__ x1, __hip_bfloat16* __restrict__ lnout)
{
  const size_t MN = (size_t)S_LEN * D_EMB;
  int row = blockIdx.x;
  int tid = threadIdx.x;
  float v[3];
  float s = 0.f, sq = 0.f;
  #pragma unroll
  for (int i = 0; i < 3; i++) {
    int col = tid + i * 256;
    size_t idx = (size_t)row * D_EMB + col;
    float a = resid[idx] + bias[col]
            + __bfloat162float(parts[idx])
            + __bfloat162float(parts[idx + MN])
            + __bfloat162float(parts[idx + 2 * MN]);
    x1[idx] = a;
    v[i] = a;
    s += a;
    sq += a * a;
  }
  #pragma unroll
  for (int off = 32; off >= 1; off >>= 1) {
    s  += __shfl_xor(s, off);
    sq += __shfl_xor(sq, off);
  }
  __shared__ float ss[4], ssq[4];
  if ((tid & 63) == 0) { ss[tid >> 6] = s; ssq[tid >> 6] = sq; }
  __syncthreads();
  s  = ss[0] + ss[1] + ss[2] + ss[3];
  sq = ssq[0] + ssq[1] + ssq[2] + ssq[3];
  float mean = s * (1.0f / D_EMB);
  float var  = sq * (1.0f / D_EMB) - mean * mean;
  float rstd = rsqrtf(var + 1e-5f);
  __hip_bfloat16* orow = lnout + (size_t)row * D_EMB;
  #pragma unroll
  for (int i = 0; i < 3; i++) {
    int col = tid + i * 256;
    orow[col] = __float2bfloat16((v[i] - mean) * rstd * g[col] + b[col]);
  }
}

// ---------------- causal flash attention v13 + setprio around MFMA clusters ----------------
#define SCL_LOG2E 0.18033688011f
template<bool SPLIT>
__global__ __launch_bounds__(512, 4) void attn_kernel(const __hip_bfloat16* __restrict__ kqv,
                                                      const __hip_bfloat16* __restrict__ vT,
                                                      __hip_bfloat16* __restrict__ y,
                                                      char* __restrict__ partial)
{
  __shared__ __hip_bfloat16 Ksm[2][64 * 64];   // [kv][d] linear, swizzled content
  __shared__ __hip_bfloat16 Vtsm[2][64 * 64];  // [d][kv] linear, swizzled content

  int bid = blockIdx.x;
  int h, gi, c;
  if (SPLIT) {
    int task = (bid >> 3) + (bid & 7) * 60;    // XCD-pinned: xcd = bid&7 owns 60 tasks
    h = task / 40;
    int t = task % 40;                          // heavy groups first
    if      (t < 16) { gi = 15 - (t >> 2);        c = t & 3; }
    else if (t < 28) { gi = 11 - (t - 16) / 3;    c = (t - 16) % 3; }
    else if (t < 36) { gi = 7  - ((t - 28) >> 1); c = (t - 28) & 1; }
    else             { gi = 3  - (t - 36);        c = 0; }
  } else {
    h = bid / 16; gi = 15 - (bid % 16); c = 0;
  }
  int ntile = 4 * gi + 4;
  int kt0 = c << 4;
  int kt1 = SPLIT ? min(kt0 + 16, ntile) : ntile;
  bool direct = SPLIT ? (gi < 4) : true;

  int tid = threadIdx.x;
  int w = tid >> 6, lane = tid & 63, lg = lane >> 4, li = lane & 15;
  int sw = li & 7;
  int qb0 = gi * 256 + w * 16;                  // slab0 base; slab1 = +128

  // staging roles: 512 thr x 16B = one full 64x64 bf16 tile per issue
  int ksr  = tid >> 3;
  int kscn = (tid & 7) ^ (ksr & 7);
  const __hip_bfloat16* kSrc0 = kqv + h * HD + (size_t)ksr * DQKV + kscn * 8;
  const __hip_bfloat16* vSrc0 = vT + (size_t)(h * HD + ksr) * S_LEN + kscn * 8;
  const size_t kTileStep = (size_t)64 * DQKV;

  // Q for both slabs (B-operand of 16x16x32: lane li = q-col, k(d) = kk*32+8*lg+j)
  short8v q8[2][2];
  #pragma unroll
  for (int g = 0; g < 2; g++) {
    const __hip_bfloat16* qp = kqv + (size_t)(qb0 + g * 128 + li) * DQKV + D_EMB + h * HD + 8 * lg;
    q8[g][0] = *(const short8v*)(qp);
    q8[g][1] = *(const short8v*)(qp + 32);
  }

  const short4v ones4 = { (short)0x3F80, (short)0x3F80, (short)0x3F80, (short)0x3F80 };
  float4v ol0 = {0.f,0.f,0.f,0.f}, ol1 = {0.f,0.f,0.f,0.f};   // l accumulators
  float4v o0[4], o1[4];
  #pragma unroll
  for (int fc = 0; fc < 4; fc++) { float4v z = {0.f,0.f,0.f,0.f}; o0[fc] = z; o1[fc] = z; }

  // prologue: stage tile kt0 into buffer 0
  gload16(kSrc0 + (size_t)kt0 * kTileStep, Ksm[0] + tid * 8);
  gload16(vSrc0 + (size_t)kt0 * 64,        Vtsm[0] + tid * 8);

  for (int kb = kt0; kb < kt1; kb++) {
    int p = kb & 1;
    __syncthreads();       // drains vmcnt: tile[p] staged; prev reads of buf[p^1] done
    if (kb + 1 < kt1) {    // prefetch next tile; drains at NEXT barrier (full overlap)
      gload16(kSrc0 + (size_t)(kb + 1) * kTileStep, Ksm[p ^ 1] + tid * 8);
      gload16(vSrc0 + (size_t)(kb + 1) * 64,        Vtsm[p ^ 1] + tid * 8);
    }

    bool act0 = (kb * 64 <= qb0 + 15);
    bool act1 = (kb * 64 <= qb0 + 128 + 15);
    if (!act1) continue;   // wave-uniform: both slabs above causal diag

    // S^T = K * Q^T for both slabs, each K frag read once
    float4v s0[4], s1[4];
    #pragma unroll
    for (int fc = 0; fc < 4; fc++) { float4v z = {0.f,0.f,0.f,0.f}; s0[fc] = z; s1[fc] = z; }
    __builtin_amdgcn_s_setprio(1);
    #pragma unroll
    for (int kk = 0; kk < 2; kk++) {
      #pragma unroll
      for (int fc = 0; fc < 4; fc++) {
        int ch = ((kk << 2) | lg) ^ sw;
        short8v kf = *(const short8v*)(Ksm[p] + (fc * 16 + li) * 64 + ch * 8);
        s0[fc] = __builtin_amdgcn_mfma_f32_16x16x32_bf16(kf, q8[0][kk], s0[fc], 0, 0, 0);
        s1[fc] = __builtin_amdgcn_mfma_f32_16x16x32_bf16(kf, q8[1][kk], s1[fc], 0, 0, 0);
      }
    }
    __builtin_amdgcn_s_setprio(0);

    // fixed-max softmax slab0: p = exp2(s*scl); mask only on the diagonal tile
    if (act0) {
      bool needmask = (kb * 64 + 63 > qb0);     // wave-uniform
      if (needmask) {
        #pragma unroll
        for (int fc = 0; fc < 4; fc++) {
          #pragma unroll
          for (int rr = 0; rr < 4; rr++) {
            float pv = fast_exp2(s0[fc][rr] * SCL_LOG2E);
            if ((kb * 64 + fc * 16 + 4 * lg + rr) > (qb0 + li)) pv = 0.f;
            s0[fc][rr] = pv;
          }
        }
      } else {
        #pragma unroll
        for (int fc = 0; fc < 4; fc++) {
          #pragma unroll
          for (int rr = 0; rr < 4; rr++)
            s0[fc][rr] = fast_exp2(s0[fc][rr] * SCL_LOG2E);
        }
      }
    }

    // fixed-max softmax slab1
    {
      int qb1 = qb0 + 128;
      bool needmask = (kb * 64 + 63 > qb1);     // wave-uniform
      if (needmask) {
        #pragma unroll
        for (int fc = 0; fc < 4; fc++) {
          #pragma unroll
          for (int rr = 0; rr < 4; rr++) {
            float pv = fast_exp2(s1[fc][rr] * SCL_LOG2E);
            if ((kb * 64 + fc * 16 + 4 * lg + rr) > (qb1 + li)) pv = 0.f;
            s1[fc][rr] = pv;
          }
        }
      } else {
        #pragma unroll
        for (int fc = 0; fc < 4; fc++) {
          #pragma unroll
          for (int rr = 0; rr < 4; rr++)
            s1[fc][rr] = fast_exp2(s1[fc][rr] * SCL_LOG2E);
        }
      }
    }

    // PV + l-sum: each V frag read once; l via ones-MFMA (matrix pipe)
    __builtin_amdgcn_s_setprio(1);
    if (act0) {
      #pragma unroll
      for (int kk = 0; kk < 4; kk++) {
        short4v pb0, pb1;
        #pragma unroll
        for (int rr = 0; rr < 4; rr++) { pb0[rr] = bf16bits(s0[kk][rr]); pb1[rr] = bf16bits(s1[kk][rr]); }
        ol0 = mfma16(ones4, pb0, ol0);
        ol1 = mfma16(ones4, pb1, ol1);
        int c2 = (kk << 1) | (lg >> 1);
        #pragma unroll
        for (int fc = 0; fc < 4; fc++) {
          short4v vf = *(const short4v*)(Vtsm[p] + (fc * 16 + li) * 64 + ((c2 ^ sw) << 3) + 4 * (lg & 1));
          o0[fc] = mfma16(vf, pb0, o0[fc]);
          o1[fc] = mfma16(vf, pb1, o1[fc]);
        }
      }
    } else {
      #pragma unroll
      for (int kk = 0; kk < 4; kk++) {
        short4v pb1;
        #pragma unroll
        for (int rr = 0; rr < 4; rr++) pb1[rr] = bf16bits(s1[kk][rr]);
        ol1 = mfma16(ones4, pb1, ol1);
        int c2 = (kk << 1) | (lg >> 1);
        #pragma unroll
        for (int fc = 0; fc < 4; fc++) {
          short4v vf = *(const short4v*)(Vtsm[p] + (fc * 16 + li) * 64 + ((c2 ^ sw) << 3) + 4 * (lg & 1));
          o1[fc] = mfma16(vf, pb1, o1[fc]);
        }
      }
    }
    __builtin_amdgcn_s_setprio(0);
  }

  if (direct) {
    float inv0 = 1.0f / ol0[0], inv1 = 1.0f / ol1[0];
    int q0 = qb0 + li;
    #pragma unroll
    for (int fc = 0; fc < 4; fc++) {
      short4v ov0, ov1;
      #pragma unroll
      for (int rr = 0; rr < 4; rr++) { ov0[rr] = bf16bits(o0[fc][rr] * inv0); ov1[rr] = bf16bits(o1[fc][rr] * inv1); }
      *reinterpret_cast<short4v*>(y + (size_t)q0 * D_EMB + h * HD + fc * 16 + 4 * lg) = ov0;
      *reinterpret_cast<short4v*>(y + (size_t)(q0 + 128) * D_EMB + h * HD + fc * 16 + 4 * lg) = ov1;
    }
  } else {
    int offg = (gi < 8) ? (gi - 4) * 2 : (gi < 12) ? 8 + (gi - 8) * 3 : 20 + (gi - 12) * 4;
    char* slot = partial + (size_t)(h * 36 + offg + c) * 33792;
    int q = (w & 3) * 16 + li;
    #pragma unroll
    for (int g = 0; g < 2; g++) {
      char* ps = slot + (size_t)(g * 2 + (w >> 2)) * 8448;
      __hip_bfloat16* pO = (__hip_bfloat16*)ps;
      float* pL = (float*)(ps + 8192);
      #pragma unroll
      for (int fc = 0; fc < 4; fc++) {
        #pragma unroll
        for (int rr = 0; rr < 4; rr++) {
          float val = g ? o1[fc][rr] : o0[fc][rr];
          pO[(fc * 16 + 4 * lg + rr) * 64 + q] = __float2bfloat16(val);
        }
      }
      if (lg == 0) pL[q] = g ? ol1[0] : ol0[0];
    }
  }
}

// ---------------- attn combine: plain sum of <=4 kv-chunks per (h, qb>=16) slab ----------------
__global__ __launch_bounds__(256) void attn_combine_kernel(const char* __restrict__ partial,
                                                           __hip_bfloat16* __restrict__ y)
{
  int task = blockIdx.x;            // 576 = 12 * 48
  int h  = task / 48;
  int qb = 16 + task % 48;          // 64-row slab index 16..63
  int gi = qb >> 2, slab = qb & 3;
  int nch = (gi >> 2) + 1;
  int offg = (gi < 8) ? (gi - 4) * 2 : (gi < 12) ? 8 + (gi - 8) * 3 : 20 + (gi - 12) * 4;
  const char* base = partial + (size_t)(h * 36 + offg) * 33792 + (size_t)slab * 8448;
  int wv = threadIdx.x >> 6;        // d-group (16 d rows)
  int lane = threadIdx.x & 63;      // q

  float L = 0.f;
  float acc[16];
  #pragma unroll
  for (int j = 0; j < 16; j++) acc[j] = 0.f;
  #pragma unroll
  for (int c = 0; c < 4; c++) {
    if (c < nch) {
      const char* cb = base + (size_t)c * 33792;
      L += ((const float*)(cb + 8192))[lane];
      const __hip_bfloat16* O = (const __hip_bfloat16*)cb;
      #pragma unroll
      for (int j = 0; j < 16; j++)
        acc[j] += __bfloat162float(O[(wv * 16 + j) * 64 + lane]);
    }
  }
  float inv = 1.0f / L;
  __hip_bfloat16* yp = y + (size_t)(qb * 64 + lane) * D_EMB + h * HD + wv * 16;
  short8v a0, a1;
  #pragma unroll
  for (int j = 0; j < 8; j++) a0[j] = bf16bits(acc[j] * inv);
  #pragma unroll
  for (int j = 0; j < 8; j++) a1[j] = bf16bits(acc[8 + j] * inv);
  *reinterpret_cast<short8v*>(yp)     = a0;
  *reinterpret_cast<short8v*>(yp + 8) = a1;
}

// ---------------- launch ----------------
extern "C" void kernel_launch(void* const* d_in, const int* in_sizes, int n_in,
                              void* d_out, int out_size, void* d_ws, size_t ws_size,
                              hipStream_t stream)
{
  const float* x      = (const float*)d_in[0];
  const float* w_qkv  = (const float*)d_in[1];
  const float* b_qkv  = (const float*)d_in[2];
  const float* w_proj = (const float*)d_in[3];
  const float* b_proj = (const float*)d_in[4];
  const float* w_fc1  = (const float*)d_in[5];
  const float* b_fc1  = (const float*)d_in[6];
  const float* w_fc2  = (const float*)d_in[7];
  const float* b_fc2  = (const float*)d_in[8];
  const float* ln1_g  = (const float*)d_in[9];
  const float* ln1_b  = (const float*)d_in[10];
  const float* ln2_g  = (const float*)d_in[11];
  const float* ln2_b  = (const float*)d_in[12];

  char* ws = (char*)d_ws;
  size_t off = 0;
  __hip_bfloat16* wqkvT = (__hip_bfloat16*)(ws + off); off += (size_t)DQKV * D_EMB * 2;
  __hip_bfloat16* wprojT= (__hip_bfloat16*)(ws + off); off += (size_t)D_EMB * D_EMB * 2;
  __hip_bfloat16* wfc1T = (__hip_bfloat16*)(ws + off); off += (size_t)DFF * D_EMB * 2;
  __hip_bfloat16* wfc2T = (__hip_bfloat16*)(ws + off); off += (size_t)D_EMB * DFF * 2;
  __hip_bfloat16* lnbuf = (__hip_bfloat16*)(ws + off); off += (size_t)S_LEN * D_EMB * 2;
  __hip_bfloat16* kqv   = (__hip_bfloat16*)(ws + off);
  __hip_bfloat16* hbuf  = kqv;                         off += (size_t)S_LEN * DQKV * 2;
  __hip_bfloat16* ybuf  = (__hip_bfloat16*)(ws + off); off += (size_t)S_LEN * D_EMB * 2;
  __hip_bfloat16* vTbuf = (__hip_bfloat16*)(ws + off); off += (size_t)S_LEN * D_EMB * 2;
  float*          x1    = (float*)(ws + off);          off += (size_t)S_LEN * D_EMB * 4;
  char*           part  = ws + off;                    // split-K bf16 planes; attn partials alias
  size_t needSplit = off + (size_t)4 * S_LEN * D_EMB * 2;   // 4 bf16 planes (25.2 MB)
  size_t needAttn  = off + (size_t)432 * 33792;             // 14.6 MB
  bool splitk  = (ws_size >= needSplit);
  bool attnSpl = (ws_size >= needAttn);
  const int MN4 = S_LEN * D_EMB / 4;
  (void)in_sizes; (void)n_in; (void)out_size;

  transpose_all_kernel<<<dim3(6912), dim3(256), 0, stream>>>(
      w_qkv, w_proj, w_fc1, w_fc2, wqkvT, wprojT, wfc1T, wfc2T);

  ln_kernel<<<dim3(S_LEN), dim3(256), 0, stream>>>(x, ln1_g, ln1_b, lnbuf);
  // qkv GEMM also emits vT (EPI 4)
  gemm_kernel<4><<<dim3((DQKV/128)*(S_LEN/128)), dim3(256), 0, stream>>>(
      lnbuf, wqkvT, b_qkv, nullptr, kqv, vTbuf, S_LEN, DQKV, D_EMB, D_EMB);

  if (attnSpl) {
    attn_kernel<true><<<dim3(480), dim3(512), 0, stream>>>(kqv, vTbuf, ybuf, part);
    attn_combine_kernel<<<dim3(576), dim3(256), 0, stream>>>(part, ybuf);
  } else {
    attn_kernel<false><<<dim3(192), dim3(512), 0, stream>>>(kqv, vTbuf, ybuf, part);
  }

  if (splitk) {
    // proj split-K x3 (bf16 partials), then fused reduce+LN (writes x1 and lnbuf)
    gemm_kernel<3><<<dim3((D_EMB/128)*(S_LEN/128)*3), dim3(256), 0, stream>>>(
        ybuf, wprojT, nullptr, nullptr, part, nullptr, S_LEN, D_EMB, D_EMB, D_EMB/3);
    reduce_ln_kernel<<<dim3(S_LEN), dim3(256), 0, stream>>>(
        (const __hip_bfloat16*)part, b_proj, x, ln2_g, ln2_b, x1, lnbuf);
  } else {
    gemm_kernel<2><<<dim3((D_EMB/128)*(S_LEN/128)), dim3(256), 0, stream>>>(
        ybuf, wprojT, b_proj, x, x1, nullptr, S_LEN, D_EMB, D_EMB, D_EMB);
    ln_kernel<<<dim3(S_LEN), dim3(256), 0, stream>>>(x1, ln2_g, ln2_b, lnbuf);
  }

  gemm_kernel<1><<<dim3((DFF/128)*(S_LEN/128)), dim3(256), 0, stream>>>(
      lnbuf, wfc1T, b_fc1, nullptr, hbuf, nullptr, S_LEN, DFF, D_EMB, D_EMB);

  if (splitk) {
    // fc2 split-K x4 (bf16 partials)
    gemm_kernel<3><<<dim3((D_EMB/128)*(S_LEN/128)*4), dim3(256), 0, stream>>>(
        hbuf, wfc2T, nullptr, nullptr, part, nullptr, S_LEN, D_EMB, DFF, DFF/4);
    reduce_kernel<4><<<dim3(1024), dim3(256), 0, stream>>>(
        (const __hip_bfloat16*)part, b_fc2, x1, (float*)d_out, MN4);
  } else {
    gemm_kernel<2><<<dim3((D_EMB/128)*(S_LEN/128)), dim3(256), 0, stream>>>(
        hbuf, wfc2T, b_fc2, x1, (float*)d_out, nullptr, S_LEN, D_EMB, DFF, DFF);
  }
}

// Round 17
// 172.918 us; speedup vs baseline: 1.1069x; 1.1069x over previous
//
#include <hip/hip_runtime.h>
#include <hip/hip_bf16.h>

#define S_LEN 4096
#define D_EMB 768
#define NH    12
#define HD    64
#define DQKV  2304
#define DFF   3072

typedef __attribute__((ext_vector_type(4))) short short4v;
typedef __attribute__((ext_vector_type(8))) short short8v;
typedef __attribute__((ext_vector_type(4))) float float4v;

static __device__ __forceinline__ float4v mfma16(short4v a, short4v b, float4v c) {
  return __builtin_amdgcn_mfma_f32_16x16x16bf16_1k(a, b, c, 0, 0, 0);
}

static __device__ __forceinline__ short bf16bits(float f) {
  __hip_bfloat16 h = __float2bfloat16(f);
  return *reinterpret_cast<short*>(&h);
}

static __device__ __forceinline__ float fast_exp2(float x) {
#if __has_builtin(__builtin_amdgcn_exp2f)
  return __builtin_amdgcn_exp2f(x);   // bare v_exp_f32
#else
  return exp2f(x);
#endif
}

// async global -> LDS, 16B per lane. LDS dest must be wave-uniform base + lane*16.
static __device__ __forceinline__ void gload16(const __hip_bfloat16* g, __hip_bfloat16* l) {
  __builtin_amdgcn_global_load_lds((const __attribute__((address_space(1))) void*)g,
                                   (__attribute__((address_space(3))) void*)l, 16, 0, 0);
}

// ---------------- LayerNorm: fp32 in -> bf16 out, one block per row ----------------
__global__ __launch_bounds__(256) void ln_kernel(const float* __restrict__ x,
    const float* __restrict__ g, const float* __restrict__ b,
    __hip_bfloat16* __restrict__ out)
{
  int row = blockIdx.x;
  int tid = threadIdx.x;
  const float* xr = x + (size_t)row * D_EMB;
  float v0 = xr[tid], v1 = xr[tid + 256], v2 = xr[tid + 512];
  float s  = v0 + v1 + v2;
  float sq = v0 * v0 + v1 * v1 + v2 * v2;
  #pragma unroll
  for (int off = 32; off >= 1; off >>= 1) {
    s  += __shfl_xor(s, off);
    sq += __shfl_xor(sq, off);
  }
  __shared__ float ss[4], ssq[4];
  if ((tid & 63) == 0) { ss[tid >> 6] = s; ssq[tid >> 6] = sq; }
  __syncthreads();
  s  = ss[0] + ss[1] + ss[2] + ss[3];
  sq = ssq[0] + ssq[1] + ssq[2] + ssq[3];
  float mean = s * (1.0f / D_EMB);
  float var  = sq * (1.0f / D_EMB) - mean * mean;
  float rstd = rsqrtf(var + 1e-5f);
  __hip_bfloat16* orow = out + (size_t)row * D_EMB;
  orow[tid]       = __float2bfloat16((v0 - mean) * rstd * g[tid]       + b[tid]);
  orow[tid + 256] = __float2bfloat16((v1 - mean) * rstd * g[tid + 256] + b[tid + 256]);
  orow[tid + 512] = __float2bfloat16((v2 - mean) * rstd * g[tid + 512] + b[tid + 512]);
}

// ---------------- merged weight transposes: fp32 [K][N] -> bf16 [N][K] ----------------
__global__ __launch_bounds__(256) void transpose_all_kernel(
    const float* __restrict__ w_qkv, const float* __restrict__ w_proj,
    const float* __restrict__ w_fc1, const float* __restrict__ w_fc2,
    __hip_bfloat16* __restrict__ wqkvT, __hip_bfloat16* __restrict__ wprojT,
    __hip_bfloat16* __restrict__ wfc1T, __hip_bfloat16* __restrict__ wfc2T)
{
  __shared__ float t[32][33];
  int bid = blockIdx.x;
  const float* in; __hip_bfloat16* out; int K, N, tt;
  if (bid < 1728)      { in = w_qkv;  out = wqkvT;  K = D_EMB; N = DQKV;  tt = bid; }
  else if (bid < 2304) { in = w_proj; out = wprojT; K = D_EMB; N = D_EMB; tt = bid - 1728; }
  else if (bid < 4608) { in = w_fc1;  out = wfc1T;  K = D_EMB; N = DFF;   tt = bid - 2304; }
  else                 { in = w_fc2;  out = wfc2T;  K = DFF;   N = D_EMB; tt = bid - 4608; }
  int nb = N >> 5;
  int bn = tt % nb, bk = tt / nb;
  int tx = threadIdx.x & 31, ty = threadIdx.x >> 5;
  #pragma unroll
  for (int i = 0; i < 4; i++)
    t[ty + 8 * i][tx] = in[(size_t)(bk * 32 + ty + 8 * i) * N + bn * 32 + tx];
  __syncthreads();
  #pragma unroll
  for (int i = 0; i < 4; i++)
    out[(size_t)(bn * 32 + ty + 8 * i) * K + bk * 32 + tx] = __float2bfloat16(t[tx][ty + 8 * i]);
}

// ---------------- GEMM (r15 single-buffer BK=64 structure + XCD-chunked tile map) ----------------
// EPI 0: +bias -> bf16   EPI 1: +bias, tanh-GELU -> bf16   EPI 2: +bias +resid -> fp32
// EPI 3: bf16 partial to Cout + split*M*N (no bias)
// EPI 4: +bias -> bf16, V-region cols (>=2*D_EMB) also scattered to vtout[d][s]
template<int EPI>
__global__ __launch_bounds__(256) void gemm_kernel(
    const __hip_bfloat16* __restrict__ A,
    const __hip_bfloat16* __restrict__ Bt,
    const float* __restrict__ bias,
    const float* __restrict__ resid,
    void* __restrict__ Cout,
    __hip_bfloat16* __restrict__ vtout,
    int M, int N, int Kfull, int kChunk)
{
  __shared__ __hip_bfloat16 Asm[128 * 64];
  __shared__ __hip_bfloat16 Bsm[128 * 64];
  int nb = N >> 7, mb = M >> 7;
  int tilesPer = nb * mb;
  int split = blockIdx.x / tilesPer;
  int b2 = blockIdx.x % tilesPer;
  // XCD-chunked bijective remap (tilesPer % 8 == 0 for all shapes used here):
  // each XCD owns a contiguous M-major run of tiles -> A panels L2-resident per XCD.
  b2 = (b2 & 7) * (tilesPer >> 3) + (b2 >> 3);
  int bx = b2 % nb, by = b2 / nb;
  int m0 = by << 7, n0 = bx << 7;
  int k0 = split * kChunk;
  int tid = threadIdx.x;
  int lane = tid & 63, lg = lane >> 4, li = lane & 15;
  int w = tid >> 6, wr = w >> 1, wc = w & 1;

  int sr  = tid >> 3;
  int scn = (tid & 7) ^ (sr & 7);
  const __hip_bfloat16* aSrc = A  + (size_t)(m0 + sr) * Kfull + k0 + scn * 8;
  const __hip_bfloat16* bSrc = Bt + (size_t)(n0 + sr) * Kfull + k0 + scn * 8;
  __hip_bfloat16* aDst = Asm + tid * 8;
  __hip_bfloat16* bDst = Bsm + tid * 8;
  const size_t rowStep = (size_t)32 * Kfull;

  float4v acc[4][4];
  #pragma unroll
  for (int i = 0; i < 4; i++)
    #pragma unroll
    for (int j = 0; j < 4; j++) {
      float4v z = {0.f, 0.f, 0.f, 0.f};
      acc[i][j] = z;
    }

  int sw = li & 7;

  for (int kt = 0; kt < kChunk; kt += 64) {
    #pragma unroll
    for (int i = 0; i < 4; i++) {
      gload16(aSrc + i * rowStep, aDst + i * 2048);
      gload16(bSrc + i * rowStep, bDst + i * 2048);
    }
    aSrc += 64; bSrc += 64;
    __syncthreads();
    #pragma unroll
    for (int kk = 0; kk < 2; kk++) {
      short8v af[4], bf[4];
      #pragma unroll
      for (int f = 0; f < 4; f++) {
        int ar = wr * 64 + f * 16 + li;
        int br = wc * 64 + f * 16 + li;
        int ch = ((kk << 2) | lg) ^ sw;
        af[f] = *(const short8v*)(Asm + ar * 64 + ch * 8);
        bf[f] = *(const short8v*)(Bsm + br * 64 + ch * 8);
      }
      #pragma unroll
      for (int fr = 0; fr < 4; fr++)
        #pragma unroll
        for (int fc = 0; fc < 4; fc++)
          acc[fr][fc] = __builtin_amdgcn_mfma_f32_16x16x32_bf16(af[fr], bf[fc], acc[fr][fc], 0, 0, 0);
    }
    __syncthreads();
  }

  #pragma unroll
  for (int fr = 0; fr < 4; fr++) {
    int row = m0 + wr * 64 + fr * 16 + lg * 4;
    #pragma unroll
    for (int fc = 0; fc < 4; fc++) {
      int col = n0 + wc * 64 + fc * 16 + li;
      float bv = (EPI == 3) ? 0.f : bias[col];
      short4v tv;
      #pragma unroll
      for (int r = 0; r < 4; r++) {
        float v = acc[fr][fc][r] + bv;
        size_t idx = (size_t)(row + r) * N + col;
        if (EPI == 1) {
          // GELU(v) ~= v * sigmoid(2u), u = 0.79788456(v + 0.044715 v^3)
          float u = 0.7978845608028654f * (v + 0.044715f * v * v * v);
          float e = fast_exp2(u * 2.8853900817779268f);   // exp(2u)
#if __has_builtin(__builtin_amdgcn_rcpf)
          float r1 = __builtin_amdgcn_rcpf(e + 1.0f);
#else
          float r1 = 1.0f / (e + 1.0f);
#endif
          v = v * e * r1;
          ((__hip_bfloat16*)Cout)[idx] = __float2bfloat16(v);
        } else if (EPI == 2) {
          ((float*)Cout)[idx] = v + resid[idx];
        } else if (EPI == 3) {
          ((__hip_bfloat16*)Cout)[(size_t)split * M * N + idx] = __float2bfloat16(v);
        } else {
          __hip_bfloat16 hb = __float2bfloat16(v);
          ((__hip_bfloat16*)Cout)[idx] = hb;
          if (EPI == 4) tv[r] = *reinterpret_cast<short*>(&hb);
        }
      }
      if (EPI == 4 && col >= 2 * D_EMB) {
        *reinterpret_cast<short4v*>(vtout + (size_t)(col - 2 * D_EMB) * S_LEN + row) = tv;
      }
    }
  }
}

// ---------------- split-K reduce (bf16 parts): out = resid + bias + sum(parts) ----------------
template<int NS>
__global__ __launch_bounds__(256) void reduce_kernel(const __hip_bfloat16* __restrict__ parts,
    const float* __restrict__ bias, const float* __restrict__ resid,
    float* __restrict__ out, int n4)
{
  const size_t MN = (size_t)S_LEN * D_EMB;
  int stride = gridDim.x * 256;
  for (int e = blockIdx.x * 256 + threadIdx.x; e < n4; e += stride) {
    float4v acc = *(const float4v*)(resid + 4 * (size_t)e);
    int col = (e * 4) % D_EMB;
    float4v bv = *(const float4v*)(bias + col);
    acc += bv;
    #pragma unroll
    for (int s = 0; s < NS; s++) {
      short4v pv = *(const short4v*)(parts + (size_t)s * MN + 4 * (size_t)e);
      #pragma unroll
      for (int j = 0; j < 4; j++) {
        unsigned int u = ((unsigned int)(unsigned short)pv[j]) << 16;
        acc[j] += *reinterpret_cast<float*>(&u);
      }
    }
    *(float4v*)(out + 4 * (size_t)e) = acc;
  }
}

// ---------------- fused split-K(3, bf16) reduce + LayerNorm ----------------
__global__ __launch_bounds__(256) void reduce_ln_kernel(const __hip_bfloat16* __restrict__ parts,
    const float* __restrict__ bias, const float* __restrict__ resid,
    const float* __restrict__ g, const float* __restrict__ b,
    float* __restrict__ x1, __hip_bfloat16* __restrict__ lnout)
{
  const size_t MN = (size_t)S_LEN * D_EMB;
  int row = blockIdx.x;
  int tid = threadIdx.x;
  float v[3];
  float s = 0.f, sq = 0.f;
  #pragma unroll
  for (int i = 0; i < 3; i++) {
    int col = tid + i * 256;
    size_t idx = (size_t)row * D_EMB + col;
    float a = resid[idx] + bias[col]
            + __bfloat162float(parts[idx])
            + __bfloat162float(parts[idx + MN])
            + __bfloat162float(parts[idx + 2 * MN]);
    x1[idx] = a;
    v[i] = a;
    s += a;
    sq += a * a;
  }
  #pragma unroll
  for (int off = 32; off >= 1; off >>= 1) {
    s  += __shfl_xor(s, off);
    sq += __shfl_xor(sq, off);
  }
  __shared__ float ss[4], ssq[4];
  if ((tid & 63) == 0) { ss[tid >> 6] = s; ssq[tid >> 6] = sq; }
  __syncthreads();
  s  = ss[0] + ss[1] + ss[2] + ss[3];
  sq = ssq[0] + ssq[1] + ssq[2] + ssq[3];
  float mean = s * (1.0f / D_EMB);
  float var  = sq * (1.0f / D_EMB) - mean * mean;
  float rstd = rsqrtf(var + 1e-5f);
  __hip_bfloat16* orow = lnout + (size_t)row * D_EMB;
  #pragma unroll
  for (int i = 0; i < 3; i++) {
    int col = tid + i * 256;
    orow[col] = __float2bfloat16((v[i] - mean) * rstd * g[col] + b[col]);
  }
}

// ---------------- causal flash attention v13 + setprio (r16 form, unchanged) ----------------
#define SCL_LOG2E 0.18033688011f
template<bool SPLIT>
__global__ __launch_bounds__(512, 4) void attn_kernel(const __hip_bfloat16* __restrict__ kqv,
                                                      const __hip_bfloat16* __restrict__ vT,
                                                      __hip_bfloat16* __restrict__ y,
                                                      char* __restrict__ partial)
{
  __shared__ __hip_bfloat16 Ksm[2][64 * 64];   // [kv][d] linear, swizzled content
  __shared__ __hip_bfloat16 Vtsm[2][64 * 64];  // [d][kv] linear, swizzled content

  int bid = blockIdx.x;
  int h, gi, c;
  if (SPLIT) {
    int task = (bid >> 3) + (bid & 7) * 60;    // XCD-pinned: xcd = bid&7 owns 60 tasks
    h = task / 40;
    int t = task % 40;                          // heavy groups first
    if      (t < 16) { gi = 15 - (t >> 2);        c = t & 3; }
    else if (t < 28) { gi = 11 - (t - 16) / 3;    c = (t - 16) % 3; }
    else if (t < 36) { gi = 7  - ((t - 28) >> 1); c = (t - 28) & 1; }
    else             { gi = 3  - (t - 36);        c = 0; }
  } else {
    h = bid / 16; gi = 15 - (bid % 16); c = 0;
  }
  int ntile = 4 * gi + 4;
  int kt0 = c << 4;
  int kt1 = SPLIT ? min(kt0 + 16, ntile) : ntile;
  bool direct = SPLIT ? (gi < 4) : true;

  int tid = threadIdx.x;
  int w = tid >> 6, lane = tid & 63, lg = lane >> 4, li = lane & 15;
  int sw = li & 7;
  int qb0 = gi * 256 + w * 16;                  // slab0 base; slab1 = +128

  // staging roles: 512 thr x 16B = one full 64x64 bf16 tile per issue
  int ksr  = tid >> 3;
  int kscn = (tid & 7) ^ (ksr & 7);
  const __hip_bfloat16* kSrc0 = kqv + h * HD + (size_t)ksr * DQKV + kscn * 8;
  const __hip_bfloat16* vSrc0 = vT + (size_t)(h * HD + ksr) * S_LEN + kscn * 8;
  const size_t kTileStep = (size_t)64 * DQKV;

  // Q for both slabs (B-operand of 16x16x32: lane li = q-col, k(d) = kk*32+8*lg+j)
  short8v q8[2][2];
  #pragma unroll
  for (int g = 0; g < 2; g++) {
    const __hip_bfloat16* qp = kqv + (size_t)(qb0 + g * 128 + li) * DQKV + D_EMB + h * HD + 8 * lg;
    q8[g][0] = *(const short8v*)(qp);
    q8[g][1] = *(const short8v*)(qp + 32);
  }

  const short4v ones4 = { (short)0x3F80, (short)0x3F80, (short)0x3F80, (short)0x3F80 };
  float4v ol0 = {0.f,0.f,0.f,0.f}, ol1 = {0.f,0.f,0.f,0.f};   // l accumulators
  float4v o0[4], o1[4];
  #pragma unroll
  for (int fc = 0; fc < 4; fc++) { float4v z = {0.f,0.f,0.f,0.f}; o0[fc] = z; o1[fc] = z; }

  // prologue: stage tile kt0 into buffer 0
  gload16(kSrc0 + (size_t)kt0 * kTileStep, Ksm[0] + tid * 8);
  gload16(vSrc0 + (size_t)kt0 * 64,        Vtsm[0] + tid * 8);

  for (int kb = kt0; kb < kt1; kb++) {
    int p = kb & 1;
    __syncthreads();       // drains vmcnt: tile[p] staged; prev reads of buf[p^1] done
    if (kb + 1 < kt1) {    // prefetch next tile; drains at NEXT barrier (full overlap)
      gload16(kSrc0 + (size_t)(kb + 1) * kTileStep, Ksm[p ^ 1] + tid * 8);
      gload16(vSrc0 + (size_t)(kb + 1) * 64,        Vtsm[p ^ 1] + tid * 8);
    }

    bool act0 = (kb * 64 <= qb0 + 15);
    bool act1 = (kb * 64 <= qb0 + 128 + 15);
    if (!act1) continue;   // wave-uniform: both slabs above causal diag

    // S^T = K * Q^T for both slabs, each K frag read once
    float4v s0[4], s1[4];
    #pragma unroll
    for (int fc = 0; fc < 4; fc++) { float4v z = {0.f,0.f,0.f,0.f}; s0[fc] = z; s1[fc] = z; }
    __builtin_amdgcn_s_setprio(1);
    #pragma unroll
    for (int kk = 0; kk < 2; kk++) {
      #pragma unroll
      for (int fc = 0; fc < 4; fc++) {
        int ch = ((kk << 2) | lg) ^ sw;
        short8v kf = *(const short8v*)(Ksm[p] + (fc * 16 + li) * 64 + ch * 8);
        s0[fc] = __builtin_amdgcn_mfma_f32_16x16x32_bf16(kf, q8[0][kk], s0[fc], 0, 0, 0);
        s1[fc] = __builtin_amdgcn_mfma_f32_16x16x32_bf16(kf, q8[1][kk], s1[fc], 0, 0, 0);
      }
    }
    __builtin_amdgcn_s_setprio(0);

    // fixed-max softmax slab0: p = exp2(s*scl); mask only on the diagonal tile
    if (act0) {
      bool needmask = (kb * 64 + 63 > qb0);     // wave-uniform
      if (needmask) {
        #pragma unroll
        for (int fc = 0; fc < 4; fc++) {
          #pragma unroll
          for (int rr = 0; rr < 4; rr++) {
            float pv = fast_exp2(s0[fc][rr] * SCL_LOG2E);
            if ((kb * 64 + fc * 16 + 4 * lg + rr) > (qb0 + li)) pv = 0.f;
            s0[fc][rr] = pv;
          }
        }
      } else {
        #pragma unroll
        for (int fc = 0; fc < 4; fc++) {
          #pragma unroll
          for (int rr = 0; rr < 4; rr++)
            s0[fc][rr] = fast_exp2(s0[fc][rr] * SCL_LOG2E);
        }
      }
    }

    // fixed-max softmax slab1
    {
      int qb1 = qb0 + 128;
      bool needmask = (kb * 64 + 63 > qb1);     // wave-uniform
      if (needmask) {
        #pragma unroll
        for (int fc = 0; fc < 4; fc++) {
          #pragma unroll
          for (int rr = 0; rr < 4; rr++) {
            float pv = fast_exp2(s1[fc][rr] * SCL_LOG2E);
            if ((kb * 64 + fc * 16 + 4 * lg + rr) > (qb1 + li)) pv = 0.f;
            s1[fc][rr] = pv;
          }
        }
      } else {
        #pragma unroll
        for (int fc = 0; fc < 4; fc++) {
          #pragma unroll
          for (int rr = 0; rr < 4; rr++)
            s1[fc][rr] = fast_exp2(s1[fc][rr] * SCL_LOG2E);
        }
      }
    }

    // PV + l-sum: each V frag read once; l via ones-MFMA (matrix pipe)
    __builtin_amdgcn_s_setprio(1);
    if (act0) {
      #pragma unroll
      for (int kk = 0; kk < 4; kk++) {
        short4v pb0, pb1;
        #pragma unroll
        for (int rr = 0; rr < 4; rr++) { pb0[rr] = bf16bits(s0[kk][rr]); pb1[rr] = bf16bits(s1[kk][rr]); }
        ol0 = mfma16(ones4, pb0, ol0);
        ol1 = mfma16(ones4, pb1, ol1);
        int c2 = (kk << 1) | (lg >> 1);
        #pragma unroll
        for (int fc = 0; fc < 4; fc++) {
          short4v vf = *(const short4v*)(Vtsm[p] + (fc * 16 + li) * 64 + ((c2 ^ sw) << 3) + 4 * (lg & 1));
          o0[fc] = mfma16(vf, pb0, o0[fc]);
          o1[fc] = mfma16(vf, pb1, o1[fc]);
        }
      }
    } else {
      #pragma unroll
      for (int kk = 0; kk < 4; kk++) {
        short4v pb1;
        #pragma unroll
        for (int rr = 0; rr < 4; rr++) pb1[rr] = bf16bits(s1[kk][rr]);
        ol1 = mfma16(ones4, pb1, ol1);
        int c2 = (kk << 1) | (lg >> 1);
        #pragma unroll
        for (int fc = 0; fc < 4; fc++) {
          short4v vf = *(const short4v*)(Vtsm[p] + (fc * 16 + li) * 64 + ((c2 ^ sw) << 3) + 4 * (lg & 1));
          o1[fc] = mfma16(vf, pb1, o1[fc]);
        }
      }
    }
    __builtin_amdgcn_s_setprio(0);
  }

  if (direct) {
    float inv0 = 1.0f / ol0[0], inv1 = 1.0f / ol1[0];
    int q0 = qb0 + li;
    #pragma unroll
    for (int fc = 0; fc < 4; fc++) {
      short4v ov0, ov1;
      #pragma unroll
      for (int rr = 0; rr < 4; rr++) { ov0[rr] = bf16bits(o0[fc][rr] * inv0); ov1[rr] = bf16bits(o1[fc][rr] * inv1); }
      *reinterpret_cast<short4v*>(y + (size_t)q0 * D_EMB + h * HD + fc * 16 + 4 * lg) = ov0;
      *reinterpret_cast<short4v*>(y + (size_t)(q0 + 128) * D_EMB + h * HD + fc * 16 + 4 * lg) = ov1;
    }
  } else {
    int offg = (gi < 8) ? (gi - 4) * 2 : (gi < 12) ? 8 + (gi - 8) * 3 : 20 + (gi - 12) * 4;
    char* slot = partial + (size_t)(h * 36 + offg + c) * 33792;
    int q = (w & 3) * 16 + li;
    #pragma unroll
    for (int g = 0; g < 2; g++) {
      char* ps = slot + (size_t)(g * 2 + (w >> 2)) * 8448;
      __hip_bfloat16* pO = (__hip_bfloat16*)ps;
      float* pL = (float*)(ps + 8192);
      #pragma unroll
      for (int fc = 0; fc < 4; fc++) {
        #pragma unroll
        for (int rr = 0; rr < 4; rr++) {
          float val = g ? o1[fc][rr] : o0[fc][rr];
          pO[(fc * 16 + 4 * lg + rr) * 64 + q] = __float2bfloat16(val);
        }
      }
      if (lg == 0) pL[q] = g ? ol1[0] : ol0[0];
    }
  }
}

// ---------------- attn combine: plain sum of <=4 kv-chunks per (h, qb>=16) slab ----------------
__global__ __launch_bounds__(256) void attn_combine_kernel(const char* __restrict__ partial,
                                                           __hip_bfloat16* __restrict__ y)
{
  int task = blockIdx.x;            // 576 = 12 * 48
  int h  = task / 48;
  int qb = 16 + task % 48;          // 64-row slab index 16..63
  int gi = qb >> 2, slab = qb & 3;
  int nch = (gi >> 2) + 1;
  int offg = (gi < 8) ? (gi - 4) * 2 : (gi < 12) ? 8 + (gi - 8) * 3 : 20 + (gi - 12) * 4;
  const char* base = partial + (size_t)(h * 36 + offg) * 33792 + (size_t)slab * 8448;
  int wv = threadIdx.x >> 6;        // d-group (16 d rows)
  int lane = threadIdx.x & 63;      // q

  float L = 0.f;
  float acc[16];
  #pragma unroll
  for (int j = 0; j < 16; j++) acc[j] = 0.f;
  #pragma unroll
  for (int c = 0; c < 4; c++) {
    if (c < nch) {
      const char* cb = base + (size_t)c * 33792;
      L += ((const float*)(cb + 8192))[lane];
      const __hip_bfloat16* O = (const __hip_bfloat16*)cb;
      #pragma unroll
      for (int j = 0; j < 16; j++)
        acc[j] += __bfloat162float(O[(wv * 16 + j) * 64 + lane]);
    }
  }
  float inv = 1.0f / L;
  __hip_bfloat16* yp = y + (size_t)(qb * 64 + lane) * D_EMB + h * HD + wv * 16;
  short8v a0, a1;
  #pragma unroll
  for (int j = 0; j < 8; j++) a0[j] = bf16bits(acc[j] * inv);
  #pragma unroll
  for (int j = 0; j < 8; j++) a1[j] = bf16bits(acc[8 + j] * inv);
  *reinterpret_cast<short8v*>(yp)     = a0;
  *reinterpret_cast<short8v*>(yp + 8) = a1;
}

// ---------------- launch ----------------
extern "C" void kernel_launch(void* const* d_in, const int* in_sizes, int n_in,
                              void* d_out, int out_size, void* d_ws, size_t ws_size,
                              hipStream_t stream)
{
  const float* x      = (const float*)d_in[0];
  const float* w_qkv  = (const float*)d_in[1];
  const float* b_qkv  = (const float*)d_in[2];
  const float* w_proj = (const float*)d_in[3];
  const float* b_proj = (const float*)d_in[4];
  const float* w_fc1  = (const float*)d_in[5];
  const float* b_fc1  = (const float*)d_in[6];
  const float* w_fc2  = (const float*)d_in[7];
  const float* b_fc2  = (const float*)d_in[8];
  const float* ln1_g  = (const float*)d_in[9];
  const float* ln1_b  = (const float*)d_in[10];
  const float* ln2_g  = (const float*)d_in[11];
  const float* ln2_b  = (const float*)d_in[12];

  char* ws = (char*)d_ws;
  size_t off = 0;
  __hip_bfloat16* wqkvT = (__hip_bfloat16*)(ws + off); off += (size_t)DQKV * D_EMB * 2;
  __hip_bfloat16* wprojT= (__hip_bfloat16*)(ws + off); off += (size_t)D_EMB * D_EMB * 2;
  __hip_bfloat16* wfc1T = (__hip_bfloat16*)(ws + off); off += (size_t)DFF * D_EMB * 2;
  __hip_bfloat16* wfc2T = (__hip_bfloat16*)(ws + off); off += (size_t)D_EMB * DFF * 2;
  __hip_bfloat16* lnbuf = (__hip_bfloat16*)(ws + off); off += (size_t)S_LEN * D_EMB * 2;
  __hip_bfloat16* kqv   = (__hip_bfloat16*)(ws + off);
  __hip_bfloat16* hbuf  = kqv;                         off += (size_t)S_LEN * DQKV * 2;
  __hip_bfloat16* ybuf  = (__hip_bfloat16*)(ws + off); off += (size_t)S_LEN * D_EMB * 2;
  __hip_bfloat16* vTbuf = (__hip_bfloat16*)(ws + off); off += (size_t)S_LEN * D_EMB * 2;
  float*          x1    = (float*)(ws + off);          off += (size_t)S_LEN * D_EMB * 4;
  char*           part  = ws + off;                    // split-K bf16 planes; attn partials alias
  size_t needSplit = off + (size_t)4 * S_LEN * D_EMB * 2;   // 4 bf16 planes (25.2 MB)
  size_t needAttn  = off + (size_t)432 * 33792;             // 14.6 MB
  bool splitk  = (ws_size >= needSplit);
  bool attnSpl = (ws_size >= needAttn);
  const int MN4 = S_LEN * D_EMB / 4;
  (void)in_sizes; (void)n_in; (void)out_size;

  transpose_all_kernel<<<dim3(6912), dim3(256), 0, stream>>>(
      w_qkv, w_proj, w_fc1, w_fc2, wqkvT, wprojT, wfc1T, wfc2T);

  ln_kernel<<<dim3(S_LEN), dim3(256), 0, stream>>>(x, ln1_g, ln1_b, lnbuf);
  // qkv GEMM also emits vT (EPI 4)
  gemm_kernel<4><<<dim3((DQKV/128)*(S_LEN/128)), dim3(256), 0, stream>>>(
      lnbuf, wqkvT, b_qkv, nullptr, kqv, vTbuf, S_LEN, DQKV, D_EMB, D_EMB);

  if (attnSpl) {
    attn_kernel<true><<<dim3(480), dim3(512), 0, stream>>>(kqv, vTbuf, ybuf, part);
    attn_combine_kernel<<<dim3(576), dim3(256), 0, stream>>>(part, ybuf);
  } else {
    attn_kernel<false><<<dim3(192), dim3(512), 0, stream>>>(kqv, vTbuf, ybuf, part);
  }

  if (splitk) {
    // proj split-K x3 (bf16 partials), then fused reduce+LN (writes x1 and lnbuf)
    gemm_kernel<3><<<dim3((D_EMB/128)*(S_LEN/128)*3), dim3(256), 0, stream>>>(
        ybuf, wprojT, nullptr, nullptr, part, nullptr, S_LEN, D_EMB, D_EMB, D_EMB/3);
    reduce_ln_kernel<<<dim3(S_LEN), dim3(256), 0, stream>>>(
        (const __hip_bfloat16*)part, b_proj, x, ln2_g, ln2_b, x1, lnbuf);
  } else {
    gemm_kernel<2><<<dim3((D_EMB/128)*(S_LEN/128)), dim3(256), 0, stream>>>(
        ybuf, wprojT, b_proj, x, x1, nullptr, S_LEN, D_EMB, D_EMB, D_EMB);
    ln_kernel<<<dim3(S_LEN), dim3(256), 0, stream>>>(x1, ln2_g, ln2_b, lnbuf);
  }

  gemm_kernel<1><<<dim3((DFF/128)*(S_LEN/128)), dim3(256), 0, stream>>>(
      lnbuf, wfc1T, b_fc1, nullptr, hbuf, nullptr, S_LEN, DFF, D_EMB, D_EMB);

  if (splitk) {
    // fc2 split-K x4 (bf16 partials)
    gemm_kernel<3><<<dim3((D_EMB/128)*(S_LEN/128)*4), dim3(256), 0, stream>>>(
        hbuf, wfc2T, nullptr, nullptr, part, nullptr, S_LEN, D_EMB, DFF, DFF/4);
    reduce_kernel<4><<<dim3(1024), dim3(256), 0, stream>>>(
        (const __hip_bfloat16*)part, b_fc2, x1, (float*)d_out, MN4);
  } else {
    gemm_kernel<2><<<dim3((D_EMB/128)*(S_LEN/128)), dim3(256), 0, stream>>>(
        hbuf, wfc2T, b_fc2, x1, (float*)d_out, nullptr, S_LEN, D_EMB, DFF, DFF);
  }
}

// Round 18
// 172.596 us; speedup vs baseline: 1.1090x; 1.0019x over previous
//
#include <hip/hip_runtime.h>
#include <hip/hip_bf16.h>

#define S_LEN 4096
#define D_EMB 768
#define NH    12
#define HD    64
#define DQKV  2304
#define DFF   3072

typedef __attribute__((ext_vector_type(4))) short short4v;
typedef __attribute__((ext_vector_type(8))) short short8v;
typedef __attribute__((ext_vector_type(4))) float float4v;

static __device__ __forceinline__ float4v mfma16(short4v a, short4v b, float4v c) {
  return __builtin_amdgcn_mfma_f32_16x16x16bf16_1k(a, b, c, 0, 0, 0);
}

static __device__ __forceinline__ short bf16bits(float f) {
  __hip_bfloat16 h = __float2bfloat16(f);
  return *reinterpret_cast<short*>(&h);
}

static __device__ __forceinline__ float fast_exp2(float x) {
#if __has_builtin(__builtin_amdgcn_exp2f)
  return __builtin_amdgcn_exp2f(x);   // bare v_exp_f32
#else
  return exp2f(x);
#endif
}

// async global -> LDS, 16B per lane. LDS dest must be wave-uniform base + lane*16.
static __device__ __forceinline__ void gload16(const __hip_bfloat16* g, __hip_bfloat16* l) {
  __builtin_amdgcn_global_load_lds((const __attribute__((address_space(1))) void*)g,
                                   (__attribute__((address_space(3))) void*)l, 16, 0, 0);
}

// ---------------- LayerNorm: fp32 in -> bf16 out, one block per row ----------------
__global__ __launch_bounds__(256) void ln_kernel(const float* __restrict__ x,
    const float* __restrict__ g, const float* __restrict__ b,
    __hip_bfloat16* __restrict__ out)
{
  int row = blockIdx.x;
  int tid = threadIdx.x;
  const float* xr = x + (size_t)row * D_EMB;
  float v0 = xr[tid], v1 = xr[tid + 256], v2 = xr[tid + 512];
  float s  = v0 + v1 + v2;
  float sq = v0 * v0 + v1 * v1 + v2 * v2;
  #pragma unroll
  for (int off = 32; off >= 1; off >>= 1) {
    s  += __shfl_xor(s, off);
    sq += __shfl_xor(sq, off);
  }
  __shared__ float ss[4], ssq[4];
  if ((tid & 63) == 0) { ss[tid >> 6] = s; ssq[tid >> 6] = sq; }
  __syncthreads();
  s  = ss[0] + ss[1] + ss[2] + ss[3];
  sq = ssq[0] + ssq[1] + ssq[2] + ssq[3];
  float mean = s * (1.0f / D_EMB);
  float var  = sq * (1.0f / D_EMB) - mean * mean;
  float rstd = rsqrtf(var + 1e-5f);
  __hip_bfloat16* orow = out + (size_t)row * D_EMB;
  orow[tid]       = __float2bfloat16((v0 - mean) * rstd * g[tid]       + b[tid]);
  orow[tid + 256] = __float2bfloat16((v1 - mean) * rstd * g[tid + 256] + b[tid + 256]);
  orow[tid + 512] = __float2bfloat16((v2 - mean) * rstd * g[tid + 512] + b[tid + 512]);
}

// ---------------- merged: weight transposes (bid<6912) + ln1 (bid>=6912) ----------------
__global__ __launch_bounds__(256) void transpose_ln_kernel(
    const float* __restrict__ w_qkv, const float* __restrict__ w_proj,
    const float* __restrict__ w_fc1, const float* __restrict__ w_fc2,
    __hip_bfloat16* __restrict__ wqkvT, __hip_bfloat16* __restrict__ wprojT,
    __hip_bfloat16* __restrict__ wfc1T, __hip_bfloat16* __restrict__ wfc2T,
    const float* __restrict__ x, const float* __restrict__ g1,
    const float* __restrict__ b1, __hip_bfloat16* __restrict__ lnout)
{
  int bid = blockIdx.x;
  int tid = threadIdx.x;
  if (bid >= 6912) {
    // ---- ln1 path ----
    int row = bid - 6912;
    const float* xr = x + (size_t)row * D_EMB;
    float v0 = xr[tid], v1 = xr[tid + 256], v2 = xr[tid + 512];
    float s  = v0 + v1 + v2;
    float sq = v0 * v0 + v1 * v1 + v2 * v2;
    #pragma unroll
    for (int off = 32; off >= 1; off >>= 1) {
      s  += __shfl_xor(s, off);
      sq += __shfl_xor(sq, off);
    }
    __shared__ float ss[4], ssq[4];
    if ((tid & 63) == 0) { ss[tid >> 6] = s; ssq[tid >> 6] = sq; }
    __syncthreads();
    s  = ss[0] + ss[1] + ss[2] + ss[3];
    sq = ssq[0] + ssq[1] + ssq[2] + ssq[3];
    float mean = s * (1.0f / D_EMB);
    float var  = sq * (1.0f / D_EMB) - mean * mean;
    float rstd = rsqrtf(var + 1e-5f);
    __hip_bfloat16* orow = lnout + (size_t)row * D_EMB;
    orow[tid]       = __float2bfloat16((v0 - mean) * rstd * g1[tid]       + b1[tid]);
    orow[tid + 256] = __float2bfloat16((v1 - mean) * rstd * g1[tid + 256] + b1[tid + 256]);
    orow[tid + 512] = __float2bfloat16((v2 - mean) * rstd * g1[tid + 512] + b1[tid + 512]);
    return;
  }
  // ---- transpose path ----
  __shared__ float t[32][33];
  const float* in; __hip_bfloat16* out; int K, N, tt;
  if (bid < 1728)      { in = w_qkv;  out = wqkvT;  K = D_EMB; N = DQKV;  tt = bid; }
  else if (bid < 2304) { in = w_proj; out = wprojT; K = D_EMB; N = D_EMB; tt = bid - 1728; }
  else if (bid < 4608) { in = w_fc1;  out = wfc1T;  K = D_EMB; N = DFF;   tt = bid - 2304; }
  else                 { in = w_fc2;  out = wfc2T;  K = DFF;   N = D_EMB; tt = bid - 4608; }
  int nb = N >> 5;
  int bn = tt % nb, bk = tt / nb;
  int tx = tid & 31, ty = tid >> 5;
  #pragma unroll
  for (int i = 0; i < 4; i++)
    t[ty + 8 * i][tx] = in[(size_t)(bk * 32 + ty + 8 * i) * N + bn * 32 + tx];
  __syncthreads();
  #pragma unroll
  for (int i = 0; i < 4; i++)
    out[(size_t)(bn * 32 + ty + 8 * i) * K + bk * 32 + tx] = __float2bfloat16(t[tx][ty + 8 * i]);
}

// ---------------- GEMM (r15 single-buffer BK=64 + XCD-chunked tile map) ----------------
// EPI 0: +bias -> bf16   EPI 1: +bias, tanh-GELU -> bf16   EPI 2: +bias +resid -> fp32
// EPI 3: bf16 partial to Cout + split*M*N (no bias)
// EPI 4: +bias -> bf16, V-region cols (>=2*D_EMB) also scattered to vtout[d][s]
template<int EPI>
__global__ __launch_bounds__(256) void gemm_kernel(
    const __hip_bfloat16* __restrict__ A,
    const __hip_bfloat16* __restrict__ Bt,
    const float* __restrict__ bias,
    const float* __restrict__ resid,
    void* __restrict__ Cout,
    __hip_bfloat16* __restrict__ vtout,
    int M, int N, int Kfull, int kChunk)
{
  __shared__ __hip_bfloat16 Asm[128 * 64];
  __shared__ __hip_bfloat16 Bsm[128 * 64];
  int nb = N >> 7, mb = M >> 7;
  int tilesPer = nb * mb;
  int split = blockIdx.x / tilesPer;
  int b2 = blockIdx.x % tilesPer;
  b2 = (b2 & 7) * (tilesPer >> 3) + (b2 >> 3);   // XCD-chunked bijective remap
  int bx = b2 % nb, by = b2 / nb;
  int m0 = by << 7, n0 = bx << 7;
  int k0 = split * kChunk;
  int tid = threadIdx.x;
  int lane = tid & 63, lg = lane >> 4, li = lane & 15;
  int w = tid >> 6, wr = w >> 1, wc = w & 1;

  int sr  = tid >> 3;
  int scn = (tid & 7) ^ (sr & 7);
  const __hip_bfloat16* aSrc = A  + (size_t)(m0 + sr) * Kfull + k0 + scn * 8;
  const __hip_bfloat16* bSrc = Bt + (size_t)(n0 + sr) * Kfull + k0 + scn * 8;
  __hip_bfloat16* aDst = Asm + tid * 8;
  __hip_bfloat16* bDst = Bsm + tid * 8;
  const size_t rowStep = (size_t)32 * Kfull;

  float4v acc[4][4];
  #pragma unroll
  for (int i = 0; i < 4; i++)
    #pragma unroll
    for (int j = 0; j < 4; j++) {
      float4v z = {0.f, 0.f, 0.f, 0.f};
      acc[i][j] = z;
    }

  int sw = li & 7;

  for (int kt = 0; kt < kChunk; kt += 64) {
    #pragma unroll
    for (int i = 0; i < 4; i++) {
      gload16(aSrc + i * rowStep, aDst + i * 2048);
      gload16(bSrc + i * rowStep, bDst + i * 2048);
    }
    aSrc += 64; bSrc += 64;
    __syncthreads();
    #pragma unroll
    for (int kk = 0; kk < 2; kk++) {
      short8v af[4], bf[4];
      #pragma unroll
      for (int f = 0; f < 4; f++) {
        int ar = wr * 64 + f * 16 + li;
        int br = wc * 64 + f * 16 + li;
        int ch = ((kk << 2) | lg) ^ sw;
        af[f] = *(const short8v*)(Asm + ar * 64 + ch * 8);
        bf[f] = *(const short8v*)(Bsm + br * 64 + ch * 8);
      }
      #pragma unroll
      for (int fr = 0; fr < 4; fr++)
        #pragma unroll
        for (int fc = 0; fc < 4; fc++)
          acc[fr][fc] = __builtin_amdgcn_mfma_f32_16x16x32_bf16(af[fr], bf[fc], acc[fr][fc], 0, 0, 0);
    }
    __syncthreads();
  }

  #pragma unroll
  for (int fr = 0; fr < 4; fr++) {
    int row = m0 + wr * 64 + fr * 16 + lg * 4;
    #pragma unroll
    for (int fc = 0; fc < 4; fc++) {
      int col = n0 + wc * 64 + fc * 16 + li;
      float bv = (EPI == 3) ? 0.f : bias[col];
      short4v tv;
      #pragma unroll
      for (int r = 0; r < 4; r++) {
        float v = acc[fr][fc][r] + bv;
        size_t idx = (size_t)(row + r) * N + col;
        if (EPI == 1) {
          float u = 0.7978845608028654f * (v + 0.044715f * v * v * v);
          float e = fast_exp2(u * 2.8853900817779268f);   // exp(2u)
#if __has_builtin(__builtin_amdgcn_rcpf)
          float r1 = __builtin_amdgcn_rcpf(e + 1.0f);
#else
          float r1 = 1.0f / (e + 1.0f);
#endif
          v = v * e * r1;
          ((__hip_bfloat16*)Cout)[idx] = __float2bfloat16(v);
        } else if (EPI == 2) {
          ((float*)Cout)[idx] = v + resid[idx];
        } else if (EPI == 3) {
          ((__hip_bfloat16*)Cout)[(size_t)split * M * N + idx] = __float2bfloat16(v);
        } else {
          __hip_bfloat16 hb = __float2bfloat16(v);
          ((__hip_bfloat16*)Cout)[idx] = hb;
          if (EPI == 4) tv[r] = *reinterpret_cast<short*>(&hb);
        }
      }
      if (EPI == 4 && col >= 2 * D_EMB) {
        *reinterpret_cast<short4v*>(vtout + (size_t)(col - 2 * D_EMB) * S_LEN + row) = tv;
      }
    }
  }
}

// ---------------- split-K reduce (bf16 parts): out = resid + bias + sum(parts) ----------------
template<int NS>
__global__ __launch_bounds__(256) void reduce_kernel(const __hip_bfloat16* __restrict__ parts,
    const float* __restrict__ bias, const float* __restrict__ resid,
    float* __restrict__ out, int n4)
{
  const size_t MN = (size_t)S_LEN * D_EMB;
  int stride = gridDim.x * 256;
  for (int e = blockIdx.x * 256 + threadIdx.x; e < n4; e += stride) {
    float4v acc = *(const float4v*)(resid + 4 * (size_t)e);
    int col = (e * 4) % D_EMB;
    float4v bv = *(const float4v*)(bias + col);
    acc += bv;
    #pragma unroll
    for (int s = 0; s < NS; s++) {
      short4v pv = *(const short4v*)(parts + (size_t)s * MN + 4 * (size_t)e);
      #pragma unroll
      for (int j = 0; j < 4; j++) {
        unsigned int u = ((unsigned int)(unsigned short)pv[j]) << 16;
        acc[j] += *reinterpret_cast<float*>(&u);
      }
    }
    *(float4v*)(out + 4 * (size_t)e) = acc;
  }
}

// ---------------- fused split-K(3, bf16) reduce + LayerNorm ----------------
__global__ __launch_bounds__(256) void reduce_ln_kernel(const __hip_bfloat16* __restrict__ parts,
    const float* __restrict__ bias, const float* __restrict__ resid,
    const float* __restrict__ g, const float* __restrict__ b,
    float* __restrict__ x1, __hip_bfloat16* __restrict__ lnout)
{
  const size_t MN = (size_t)S_LEN * D_EMB;
  int row = blockIdx.x;
  int tid = threadIdx.x;
  float v[3];
  float s = 0.f, sq = 0.f;
  #pragma unroll
  for (int i = 0; i < 3; i++) {
    int col = tid + i * 256;
    size_t idx = (size_t)row * D_EMB + col;
    float a = resid[idx] + bias[col]
            + __bfloat162float(parts[idx])
            + __bfloat162float(parts[idx + MN])
            + __bfloat162float(parts[idx + 2 * MN]);
    x1[idx] = a;
    v[i] = a;
    s += a;
    sq += a * a;
  }
  #pragma unroll
  for (int off = 32; off >= 1; off >>= 1) {
    s  += __shfl_xor(s, off);
    sq += __shfl_xor(sq, off);
  }
  __shared__ float ss[4], ssq[4];
  if ((tid & 63) == 0) { ss[tid >> 6] = s; ssq[tid >> 6] = sq; }
  __syncthreads();
  s  = ss[0] + ss[1] + ss[2] + ss[3];
  sq = ssq[0] + ssq[1] + ssq[2] + ssq[3];
  float mean = s * (1.0f / D_EMB);
  float var  = sq * (1.0f / D_EMB) - mean * mean;
  float rstd = rsqrtf(var + 1e-5f);
  __hip_bfloat16* orow = lnout + (size_t)row * D_EMB;
  #pragma unroll
  for (int i = 0; i < 3; i++) {
    int col = tid + i * 256;
    orow[col] = __float2bfloat16((v[i] - mean) * rstd * g[col] + b[col]);
  }
}

// ---------------- causal flash attention v13 + setprio (unchanged) ----------------
#define SCL_LOG2E 0.18033688011f
template<bool SPLIT>
__global__ __launch_bounds__(512, 4) void attn_kernel(const __hip_bfloat16* __restrict__ kqv,
                                                      const __hip_bfloat16* __restrict__ vT,
                                                      __hip_bfloat16* __restrict__ y,
                                                      char* __restrict__ partial)
{
  __shared__ __hip_bfloat16 Ksm[2][64 * 64];   // [kv][d] linear, swizzled content
  __shared__ __hip_bfloat16 Vtsm[2][64 * 64];  // [d][kv] linear, swizzled content

  int bid = blockIdx.x;
  int h, gi, c;
  if (SPLIT) {
    int task = (bid >> 3) + (bid & 7) * 60;    // XCD-pinned: xcd = bid&7 owns 60 tasks
    h = task / 40;
    int t = task % 40;                          // heavy groups first
    if      (t < 16) { gi = 15 - (t >> 2);        c = t & 3; }
    else if (t < 28) { gi = 11 - (t - 16) / 3;    c = (t - 16) % 3; }
    else if (t < 36) { gi = 7  - ((t - 28) >> 1); c = (t - 28) & 1; }
    else             { gi = 3  - (t - 36);        c = 0; }
  } else {
    h = bid / 16; gi = 15 - (bid % 16); c = 0;
  }
  int ntile = 4 * gi + 4;
  int kt0 = c << 4;
  int kt1 = SPLIT ? min(kt0 + 16, ntile) : ntile;
  bool direct = SPLIT ? (gi < 4) : true;

  int tid = threadIdx.x;
  int w = tid >> 6, lane = tid & 63, lg = lane >> 4, li = lane & 15;
  int sw = li & 7;
  int qb0 = gi * 256 + w * 16;                  // slab0 base; slab1 = +128

  int ksr  = tid >> 3;
  int kscn = (tid & 7) ^ (ksr & 7);
  const __hip_bfloat16* kSrc0 = kqv + h * HD + (size_t)ksr * DQKV + kscn * 8;
  const __hip_bfloat16* vSrc0 = vT + (size_t)(h * HD + ksr) * S_LEN + kscn * 8;
  const size_t kTileStep = (size_t)64 * DQKV;

  short8v q8[2][2];
  #pragma unroll
  for (int g = 0; g < 2; g++) {
    const __hip_bfloat16* qp = kqv + (size_t)(qb0 + g * 128 + li) * DQKV + D_EMB + h * HD + 8 * lg;
    q8[g][0] = *(const short8v*)(qp);
    q8[g][1] = *(const short8v*)(qp + 32);
  }

  const short4v ones4 = { (short)0x3F80, (short)0x3F80, (short)0x3F80, (short)0x3F80 };
  float4v ol0 = {0.f,0.f,0.f,0.f}, ol1 = {0.f,0.f,0.f,0.f};
  float4v o0[4], o1[4];
  #pragma unroll
  for (int fc = 0; fc < 4; fc++) { float4v z = {0.f,0.f,0.f,0.f}; o0[fc] = z; o1[fc] = z; }

  gload16(kSrc0 + (size_t)kt0 * kTileStep, Ksm[0] + tid * 8);
  gload16(vSrc0 + (size_t)kt0 * 64,        Vtsm[0] + tid * 8);

  for (int kb = kt0; kb < kt1; kb++) {
    int p = kb & 1;
    __syncthreads();
    if (kb + 1 < kt1) {
      gload16(kSrc0 + (size_t)(kb + 1) * kTileStep, Ksm[p ^ 1] + tid * 8);
      gload16(vSrc0 + (size_t)(kb + 1) * 64,        Vtsm[p ^ 1] + tid * 8);
    }

    bool act0 = (kb * 64 <= qb0 + 15);
    bool act1 = (kb * 64 <= qb0 + 128 + 15);
    if (!act1) continue;

    float4v s0[4], s1[4];
    #pragma unroll
    for (int fc = 0; fc < 4; fc++) { float4v z = {0.f,0.f,0.f,0.f}; s0[fc] = z; s1[fc] = z; }
    __builtin_amdgcn_s_setprio(1);
    #pragma unroll
    for (int kk = 0; kk < 2; kk++) {
      #pragma unroll
      for (int fc = 0; fc < 4; fc++) {
        int ch = ((kk << 2) | lg) ^ sw;
        short8v kf = *(const short8v*)(Ksm[p] + (fc * 16 + li) * 64 + ch * 8);
        s0[fc] = __builtin_amdgcn_mfma_f32_16x16x32_bf16(kf, q8[0][kk], s0[fc], 0, 0, 0);
        s1[fc] = __builtin_amdgcn_mfma_f32_16x16x32_bf16(kf, q8[1][kk], s1[fc], 0, 0, 0);
      }
    }
    __builtin_amdgcn_s_setprio(0);

    if (act0) {
      bool needmask = (kb * 64 + 63 > qb0);
      if (needmask) {
        #pragma unroll
        for (int fc = 0; fc < 4; fc++) {
          #pragma unroll
          for (int rr = 0; rr < 4; rr++) {
            float pv = fast_exp2(s0[fc][rr] * SCL_LOG2E);
            if ((kb * 64 + fc * 16 + 4 * lg + rr) > (qb0 + li)) pv = 0.f;
            s0[fc][rr] = pv;
          }
        }
      } else {
        #pragma unroll
        for (int fc = 0; fc < 4; fc++) {
          #pragma unroll
          for (int rr = 0; rr < 4; rr++)
            s0[fc][rr] = fast_exp2(s0[fc][rr] * SCL_LOG2E);
        }
      }
    }

    {
      int qb1 = qb0 + 128;
      bool needmask = (kb * 64 + 63 > qb1);
      if (needmask) {
        #pragma unroll
        for (int fc = 0; fc < 4; fc++) {
          #pragma unroll
          for (int rr = 0; rr < 4; rr++) {
            float pv = fast_exp2(s1[fc][rr] * SCL_LOG2E);
            if ((kb * 64 + fc * 16 + 4 * lg + rr) > (qb1 + li)) pv = 0.f;
            s1[fc][rr] = pv;
          }
        }
      } else {
        #pragma unroll
        for (int fc = 0; fc < 4; fc++) {
          #pragma unroll
          for (int rr = 0; rr < 4; rr++)
            s1[fc][rr] = fast_exp2(s1[fc][rr] * SCL_LOG2E);
        }
      }
    }

    __builtin_amdgcn_s_setprio(1);
    if (act0) {
      #pragma unroll
      for (int kk = 0; kk < 4; kk++) {
        short4v pb0, pb1;
        #pragma unroll
        for (int rr = 0; rr < 4; rr++) { pb0[rr] = bf16bits(s0[kk][rr]); pb1[rr] = bf16bits(s1[kk][rr]); }
        ol0 = mfma16(ones4, pb0, ol0);
        ol1 = mfma16(ones4, pb1, ol1);
        int c2 = (kk << 1) | (lg >> 1);
        #pragma unroll
        for (int fc = 0; fc < 4; fc++) {
          short4v vf = *(const short4v*)(Vtsm[p] + (fc * 16 + li) * 64 + ((c2 ^ sw) << 3) + 4 * (lg & 1));
          o0[fc] = mfma16(vf, pb0, o0[fc]);
          o1[fc] = mfma16(vf, pb1, o1[fc]);
        }
      }
    } else {
      #pragma unroll
      for (int kk = 0; kk < 4; kk++) {
        short4v pb1;
        #pragma unroll
        for (int rr = 0; rr < 4; rr++) pb1[rr] = bf16bits(s1[kk][rr]);
        ol1 = mfma16(ones4, pb1, ol1);
        int c2 = (kk << 1) | (lg >> 1);
        #pragma unroll
        for (int fc = 0; fc < 4; fc++) {
          short4v vf = *(const short4v*)(Vtsm[p] + (fc * 16 + li) * 64 + ((c2 ^ sw) << 3) + 4 * (lg & 1));
          o1[fc] = mfma16(vf, pb1, o1[fc]);
        }
      }
    }
    __builtin_amdgcn_s_setprio(0);
  }

  if (direct) {
    float inv0 = 1.0f / ol0[0], inv1 = 1.0f / ol1[0];
    int q0 = qb0 + li;
    #pragma unroll
    for (int fc = 0; fc < 4; fc++) {
      short4v ov0, ov1;
      #pragma unroll
      for (int rr = 0; rr < 4; rr++) { ov0[rr] = bf16bits(o0[fc][rr] * inv0); ov1[rr] = bf16bits(o1[fc][rr] * inv1); }
      *reinterpret_cast<short4v*>(y + (size_t)q0 * D_EMB + h * HD + fc * 16 + 4 * lg) = ov0;
      *reinterpret_cast<short4v*>(y + (size_t)(q0 + 128) * D_EMB + h * HD + fc * 16 + 4 * lg) = ov1;
    }
  } else {
    int offg = (gi < 8) ? (gi - 4) * 2 : (gi < 12) ? 8 + (gi - 8) * 3 : 20 + (gi - 12) * 4;
    char* slot = partial + (size_t)(h * 36 + offg + c) * 33792;
    int q = (w & 3) * 16 + li;
    #pragma unroll
    for (int g = 0; g < 2; g++) {
      char* ps = slot + (size_t)(g * 2 + (w >> 2)) * 8448;
      __hip_bfloat16* pO = (__hip_bfloat16*)ps;
      float* pL = (float*)(ps + 8192);
      #pragma unroll
      for (int fc = 0; fc < 4; fc++) {
        #pragma unroll
        for (int rr = 0; rr < 4; rr++) {
          float val = g ? o1[fc][rr] : o0[fc][rr];
          pO[(fc * 16 + 4 * lg + rr) * 64 + q] = __float2bfloat16(val);
        }
      }
      if (lg == 0) pL[q] = g ? ol1[0] : ol0[0];
    }
  }
}

// ---------------- attn combine: plain sum of <=4 kv-chunks per (h, qb>=16) slab ----------------
__global__ __launch_bounds__(256) void attn_combine_kernel(const char* __restrict__ partial,
                                                           __hip_bfloat16* __restrict__ y)
{
  int task = blockIdx.x;            // 576 = 12 * 48
  int h  = task / 48;
  int qb = 16 + task % 48;
  int gi = qb >> 2, slab = qb & 3;
  int nch = (gi >> 2) + 1;
  int offg = (gi < 8) ? (gi - 4) * 2 : (gi < 12) ? 8 + (gi - 8) * 3 : 20 + (gi - 12) * 4;
  const char* base = partial + (size_t)(h * 36 + offg) * 33792 + (size_t)slab * 8448;
  int wv = threadIdx.x >> 6;
  int lane = threadIdx.x & 63;

  float L = 0.f;
  float acc[16];
  #pragma unroll
  for (int j = 0; j < 16; j++) acc[j] = 0.f;
  #pragma unroll
  for (int c = 0; c < 4; c++) {
    if (c < nch) {
      const char* cb = base + (size_t)c * 33792;
      L += ((const float*)(cb + 8192))[lane];
      const __hip_bfloat16* O = (const __hip_bfloat16*)cb;
      #pragma unroll
      for (int j = 0; j < 16; j++)
        acc[j] += __bfloat162float(O[(wv * 16 + j) * 64 + lane]);
    }
  }
  float inv = 1.0f / L;
  __hip_bfloat16* yp = y + (size_t)(qb * 64 + lane) * D_EMB + h * HD + wv * 16;
  short8v a0, a1;
  #pragma unroll
  for (int j = 0; j < 8; j++) a0[j] = bf16bits(acc[j] * inv);
  #pragma unroll
  for (int j = 0; j < 8; j++) a1[j] = bf16bits(acc[8 + j] * inv);
  *reinterpret_cast<short8v*>(yp)     = a0;
  *reinterpret_cast<short8v*>(yp + 8) = a1;
}

// ---------------- launch ----------------
extern "C" void kernel_launch(void* const* d_in, const int* in_sizes, int n_in,
                              void* d_out, int out_size, void* d_ws, size_t ws_size,
                              hipStream_t stream)
{
  const float* x      = (const float*)d_in[0];
  const float* w_qkv  = (const float*)d_in[1];
  const float* b_qkv  = (const float*)d_in[2];
  const float* w_proj = (const float*)d_in[3];
  const float* b_proj = (const float*)d_in[4];
  const float* w_fc1  = (const float*)d_in[5];
  const float* b_fc1  = (const float*)d_in[6];
  const float* w_fc2  = (const float*)d_in[7];
  const float* b_fc2  = (const float*)d_in[8];
  const float* ln1_g  = (const float*)d_in[9];
  const float* ln1_b  = (const float*)d_in[10];
  const float* ln2_g  = (const float*)d_in[11];
  const float* ln2_b  = (const float*)d_in[12];

  char* ws = (char*)d_ws;
  size_t off = 0;
  __hip_bfloat16* wqkvT = (__hip_bfloat16*)(ws + off); off += (size_t)DQKV * D_EMB * 2;
  __hip_bfloat16* wprojT= (__hip_bfloat16*)(ws + off); off += (size_t)D_EMB * D_EMB * 2;
  __hip_bfloat16* wfc1T = (__hip_bfloat16*)(ws + off); off += (size_t)DFF * D_EMB * 2;
  __hip_bfloat16* wfc2T = (__hip_bfloat16*)(ws + off); off += (size_t)D_EMB * DFF * 2;
  __hip_bfloat16* lnbuf = (__hip_bfloat16*)(ws + off); off += (size_t)S_LEN * D_EMB * 2;
  __hip_bfloat16* kqv   = (__hip_bfloat16*)(ws + off);
  __hip_bfloat16* hbuf  = kqv;                         off += (size_t)S_LEN * DQKV * 2;
  __hip_bfloat16* ybuf  = (__hip_bfloat16*)(ws + off); off += (size_t)S_LEN * D_EMB * 2;
  __hip_bfloat16* vTbuf = (__hip_bfloat16*)(ws + off); off += (size_t)S_LEN * D_EMB * 2;
  float*          x1    = (float*)(ws + off);          off += (size_t)S_LEN * D_EMB * 4;
  char*           part  = ws + off;                    // split-K bf16 planes; attn partials alias
  size_t needSplit = off + (size_t)3 * S_LEN * D_EMB * 2;   // 3 bf16 planes (18.9 MB)
  size_t needAttn  = off + (size_t)432 * 33792;             // 14.6 MB
  bool splitk  = (ws_size >= needSplit);
  bool attnSpl = (ws_size >= needAttn);
  const int MN4 = S_LEN * D_EMB / 4;
  (void)in_sizes; (void)n_in; (void)out_size;

  // merged weight transposes + ln1 (independent work, one launch)
  transpose_ln_kernel<<<dim3(6912 + S_LEN), dim3(256), 0, stream>>>(
      w_qkv, w_proj, w_fc1, w_fc2, wqkvT, wprojT, wfc1T, wfc2T,
      x, ln1_g, ln1_b, lnbuf);

  // qkv GEMM also emits vT (EPI 4)
  gemm_kernel<4><<<dim3((DQKV/128)*(S_LEN/128)), dim3(256), 0, stream>>>(
      lnbuf, wqkvT, b_qkv, nullptr, kqv, vTbuf, S_LEN, DQKV, D_EMB, D_EMB);

  if (attnSpl) {
    attn_kernel<true><<<dim3(480), dim3(512), 0, stream>>>(kqv, vTbuf, ybuf, part);
    attn_combine_kernel<<<dim3(576), dim3(256), 0, stream>>>(part, ybuf);
  } else {
    attn_kernel<false><<<dim3(192), dim3(512), 0, stream>>>(kqv, vTbuf, ybuf, part);
  }

  if (splitk) {
    // proj split-K x3 (bf16 partials), then fused reduce+LN (writes x1 and lnbuf)
    gemm_kernel<3><<<dim3((D_EMB/128)*(S_LEN/128)*3), dim3(256), 0, stream>>>(
        ybuf, wprojT, nullptr, nullptr, part, nullptr, S_LEN, D_EMB, D_EMB, D_EMB/3);
    reduce_ln_kernel<<<dim3(S_LEN), dim3(256), 0, stream>>>(
        (const __hip_bfloat16*)part, b_proj, x, ln2_g, ln2_b, x1, lnbuf);
  } else {
    gemm_kernel<2><<<dim3((D_EMB/128)*(S_LEN/128)), dim3(256), 0, stream>>>(
        ybuf, wprojT, b_proj, x, x1, nullptr, S_LEN, D_EMB, D_EMB, D_EMB);
    ln_kernel<<<dim3(S_LEN), dim3(256), 0, stream>>>(x1, ln2_g, ln2_b, lnbuf);
  }

  gemm_kernel<1><<<dim3((DFF/128)*(S_LEN/128)), dim3(256), 0, stream>>>(
      lnbuf, wfc1T, b_fc1, nullptr, hbuf, nullptr, S_LEN, DFF, D_EMB, D_EMB);

  if (splitk) {
    // fc2 split-K x3 (bf16 partials, 576 blocks)
    gemm_kernel<3><<<dim3((D_EMB/128)*(S_LEN/128)*3), dim3(256), 0, stream>>>(
        hbuf, wfc2T, nullptr, nullptr, part, nullptr, S_LEN, D_EMB, DFF, DFF/3);
    reduce_kernel<3><<<dim3(1024), dim3(256), 0, stream>>>(
        (const __hip_bfloat16*)part, b_fc2, x1, (float*)d_out, MN4);
  } else {
    gemm_kernel<2><<<dim3((D_EMB/128)*(S_LEN/128)), dim3(256), 0, stream>>>(
        hbuf, wfc2T, b_fc2, x1, (float*)d_out, nullptr, S_LEN, D_EMB, DFF, DFF);
  }
}

// Round 19
// 171.977 us; speedup vs baseline: 1.1130x; 1.0036x over previous
//
#include <hip/hip_runtime.h>
#include <hip/hip_bf16.h>

#define S_LEN 4096
#define D_EMB 768
#define NH    12
#define HD    64
#define DQKV  2304
#define DFF   3072

typedef __attribute__((ext_vector_type(4))) short short4v;
typedef __attribute__((ext_vector_type(8))) short short8v;
typedef __attribute__((ext_vector_type(4))) float float4v;

static __device__ __forceinline__ float4v mfma16(short4v a, short4v b, float4v c) {
  return __builtin_amdgcn_mfma_f32_16x16x16bf16_1k(a, b, c, 0, 0, 0);
}

static __device__ __forceinline__ short bf16bits(float f) {
  __hip_bfloat16 h = __float2bfloat16(f);
  return *reinterpret_cast<short*>(&h);
}

static __device__ __forceinline__ float fast_exp2(float x) {
#if __has_builtin(__builtin_amdgcn_exp2f)
  return __builtin_amdgcn_exp2f(x);   // bare v_exp_f32
#else
  return exp2f(x);
#endif
}

// async global -> LDS, 16B per lane. LDS dest must be wave-uniform base + lane*16.
static __device__ __forceinline__ void gload16(const __hip_bfloat16* g, __hip_bfloat16* l) {
  __builtin_amdgcn_global_load_lds((const __attribute__((address_space(1))) void*)g,
                                   (__attribute__((address_space(3))) void*)l, 16, 0, 0);
}

// ---------------- LayerNorm: fp32 in -> bf16 out, one block per row (fallback path) ----------------
__global__ __launch_bounds__(256) void ln_kernel(const float* __restrict__ x,
    const float* __restrict__ g, const float* __restrict__ b,
    __hip_bfloat16* __restrict__ out)
{
  int row = blockIdx.x;
  int tid = threadIdx.x;
  const float* xr = x + (size_t)row * D_EMB;
  float v0 = xr[tid], v1 = xr[tid + 256], v2 = xr[tid + 512];
  float s  = v0 + v1 + v2;
  float sq = v0 * v0 + v1 * v1 + v2 * v2;
  #pragma unroll
  for (int off = 32; off >= 1; off >>= 1) {
    s  += __shfl_xor(s, off);
    sq += __shfl_xor(sq, off);
  }
  __shared__ float ss[4], ssq[4];
  if ((tid & 63) == 0) { ss[tid >> 6] = s; ssq[tid >> 6] = sq; }
  __syncthreads();
  s  = ss[0] + ss[1] + ss[2] + ss[3];
  sq = ssq[0] + ssq[1] + ssq[2] + ssq[3];
  float mean = s * (1.0f / D_EMB);
  float var  = sq * (1.0f / D_EMB) - mean * mean;
  float rstd = rsqrtf(var + 1e-5f);
  __hip_bfloat16* orow = out + (size_t)row * D_EMB;
  orow[tid]       = __float2bfloat16((v0 - mean) * rstd * g[tid]       + b[tid]);
  orow[tid + 256] = __float2bfloat16((v1 - mean) * rstd * g[tid + 256] + b[tid + 256]);
  orow[tid + 512] = __float2bfloat16((v2 - mean) * rstd * g[tid + 512] + b[tid + 512]);
}

// ---------------- merged: weight transposes (bid<6912) + ln1 (bid>=6912) ----------------
__global__ __launch_bounds__(256) void transpose_ln_kernel(
    const float* __restrict__ w_qkv, const float* __restrict__ w_proj,
    const float* __restrict__ w_fc1, const float* __restrict__ w_fc2,
    __hip_bfloat16* __restrict__ wqkvT, __hip_bfloat16* __restrict__ wprojT,
    __hip_bfloat16* __restrict__ wfc1T, __hip_bfloat16* __restrict__ wfc2T,
    const float* __restrict__ x, const float* __restrict__ g1,
    const float* __restrict__ b1, __hip_bfloat16* __restrict__ lnout)
{
  int bid = blockIdx.x;
  int tid = threadIdx.x;
  if (bid >= 6912) {
    // ---- ln1 path ----
    int row = bid - 6912;
    const float* xr = x + (size_t)row * D_EMB;
    float v0 = xr[tid], v1 = xr[tid + 256], v2 = xr[tid + 512];
    float s  = v0 + v1 + v2;
    float sq = v0 * v0 + v1 * v1 + v2 * v2;
    #pragma unroll
    for (int off = 32; off >= 1; off >>= 1) {
      s  += __shfl_xor(s, off);
      sq += __shfl_xor(sq, off);
    }
    __shared__ float ss[4], ssq[4];
    if ((tid & 63) == 0) { ss[tid >> 6] = s; ssq[tid >> 6] = sq; }
    __syncthreads();
    s  = ss[0] + ss[1] + ss[2] + ss[3];
    sq = ssq[0] + ssq[1] + ssq[2] + ssq[3];
    float mean = s * (1.0f / D_EMB);
    float var  = sq * (1.0f / D_EMB) - mean * mean;
    float rstd = rsqrtf(var + 1e-5f);
    __hip_bfloat16* orow = lnout + (size_t)row * D_EMB;
    orow[tid]       = __float2bfloat16((v0 - mean) * rstd * g1[tid]       + b1[tid]);
    orow[tid + 256] = __float2bfloat16((v1 - mean) * rstd * g1[tid + 256] + b1[tid + 256]);
    orow[tid + 512] = __float2bfloat16((v2 - mean) * rstd * g1[tid + 512] + b1[tid + 512]);
    return;
  }
  // ---- transpose path ----
  __shared__ float t[32][33];
  const float* in; __hip_bfloat16* out; int K, N, tt;
  if (bid < 1728)      { in = w_qkv;  out = wqkvT;  K = D_EMB; N = DQKV;  tt = bid; }
  else if (bid < 2304) { in = w_proj; out = wprojT; K = D_EMB; N = D_EMB; tt = bid - 1728; }
  else if (bid < 4608) { in = w_fc1;  out = wfc1T;  K = D_EMB; N = DFF;   tt = bid - 2304; }
  else                 { in = w_fc2;  out = wfc2T;  K = DFF;   N = D_EMB; tt = bid - 4608; }
  int nb = N >> 5;
  int bn = tt % nb, bk = tt / nb;
  int tx = tid & 31, ty = tid >> 5;
  #pragma unroll
  for (int i = 0; i < 4; i++)
    t[ty + 8 * i][tx] = in[(size_t)(bk * 32 + ty + 8 * i) * N + bn * 32 + tx];
  __syncthreads();
  #pragma unroll
  for (int i = 0; i < 4; i++)
    out[(size_t)(bn * 32 + ty + 8 * i) * K + bk * 32 + tx] = __float2bfloat16(t[tx][ty + 8 * i]);
}

// ---------------- GEMM (single-buffer BK=64 + XCD-chunked tile map) ----------------
// EPI 0: +bias -> bf16   EPI 1: +bias, tanh-GELU -> bf16   EPI 2: +bias +resid -> fp32
// EPI 3: bf16 partial to Cout + split*M*N (no bias)
// EPI 4: +bias -> bf16, V-region cols (>=2*D_EMB) also scattered to vtout[d][s]
template<int EPI>
__global__ __launch_bounds__(256) void gemm_kernel(
    const __hip_bfloat16* __restrict__ A,
    const __hip_bfloat16* __restrict__ Bt,
    const float* __restrict__ bias,
    const float* __restrict__ resid,
    void* __restrict__ Cout,
    __hip_bfloat16* __restrict__ vtout,
    int M, int N, int Kfull, int kChunk)
{
  __shared__ __hip_bfloat16 Asm[128 * 64];
  __shared__ __hip_bfloat16 Bsm[128 * 64];
  int nb = N >> 7, mb = M >> 7;
  int tilesPer = nb * mb;
  int split = blockIdx.x / tilesPer;
  int b2 = blockIdx.x % tilesPer;
  b2 = (b2 & 7) * (tilesPer >> 3) + (b2 >> 3);   // XCD-chunked bijective remap
  int bx = b2 % nb, by = b2 / nb;
  int m0 = by << 7, n0 = bx << 7;
  int k0 = split * kChunk;
  int tid = threadIdx.x;
  int lane = tid & 63, lg = lane >> 4, li = lane & 15;
  int w = tid >> 6, wr = w >> 1, wc = w & 1;

  int sr  = tid >> 3;
  int scn = (tid & 7) ^ (sr & 7);
  const __hip_bfloat16* aSrc = A  + (size_t)(m0 + sr) * Kfull + k0 + scn * 8;
  const __hip_bfloat16* bSrc = Bt + (size_t)(n0 + sr) * Kfull + k0 + scn * 8;
  __hip_bfloat16* aDst = Asm + tid * 8;
  __hip_bfloat16* bDst = Bsm + tid * 8;
  const size_t rowStep = (size_t)32 * Kfull;

  float4v acc[4][4];
  #pragma unroll
  for (int i = 0; i < 4; i++)
    #pragma unroll
    for (int j = 0; j < 4; j++) {
      float4v z = {0.f, 0.f, 0.f, 0.f};
      acc[i][j] = z;
    }

  int sw = li & 7;

  for (int kt = 0; kt < kChunk; kt += 64) {
    #pragma unroll
    for (int i = 0; i < 4; i++) {
      gload16(aSrc + i * rowStep, aDst + i * 2048);
      gload16(bSrc + i * rowStep, bDst + i * 2048);
    }
    aSrc += 64; bSrc += 64;
    __syncthreads();
    #pragma unroll
    for (int kk = 0; kk < 2; kk++) {
      short8v af[4], bf[4];
      #pragma unroll
      for (int f = 0; f < 4; f++) {
        int ar = wr * 64 + f * 16 + li;
        int br = wc * 64 + f * 16 + li;
        int ch = ((kk << 2) | lg) ^ sw;
        af[f] = *(const short8v*)(Asm + ar * 64 + ch * 8);
        bf[f] = *(const short8v*)(Bsm + br * 64 + ch * 8);
      }
      #pragma unroll
      for (int fr = 0; fr < 4; fr++)
        #pragma unroll
        for (int fc = 0; fc < 4; fc++)
          acc[fr][fc] = __builtin_amdgcn_mfma_f32_16x16x32_bf16(af[fr], bf[fc], acc[fr][fc], 0, 0, 0);
    }
    __syncthreads();
  }

  #pragma unroll
  for (int fr = 0; fr < 4; fr++) {
    int row = m0 + wr * 64 + fr * 16 + lg * 4;
    #pragma unroll
    for (int fc = 0; fc < 4; fc++) {
      int col = n0 + wc * 64 + fc * 16 + li;
      float bv = (EPI == 3) ? 0.f : bias[col];
      short4v tv;
      #pragma unroll
      for (int r = 0; r < 4; r++) {
        float v = acc[fr][fc][r] + bv;
        size_t idx = (size_t)(row + r) * N + col;
        if (EPI == 1) {
          float u = 0.7978845608028654f * (v + 0.044715f * v * v * v);
          float e = fast_exp2(u * 2.8853900817779268f);   // exp(2u)
#if __has_builtin(__builtin_amdgcn_rcpf)
          float r1 = __builtin_amdgcn_rcpf(e + 1.0f);
#else
          float r1 = 1.0f / (e + 1.0f);
#endif
          v = v * e * r1;
          ((__hip_bfloat16*)Cout)[idx] = __float2bfloat16(v);
        } else if (EPI == 2) {
          ((float*)Cout)[idx] = v + resid[idx];
        } else if (EPI == 3) {
          ((__hip_bfloat16*)Cout)[(size_t)split * M * N + idx] = __float2bfloat16(v);
        } else {
          __hip_bfloat16 hb = __float2bfloat16(v);
          ((__hip_bfloat16*)Cout)[idx] = hb;
          if (EPI == 4) tv[r] = *reinterpret_cast<short*>(&hb);
        }
      }
      if (EPI == 4 && col >= 2 * D_EMB) {
        *reinterpret_cast<short4v*>(vtout + (size_t)(col - 2 * D_EMB) * S_LEN + row) = tv;
      }
    }
  }
}

// ---------------- split-K reduce (bf16 parts, bf16 resid): out = resid + bias + sum(parts) ----------------
template<int NS>
__global__ __launch_bounds__(256) void reduce_kernel(const __hip_bfloat16* __restrict__ parts,
    const float* __restrict__ bias, const __hip_bfloat16* __restrict__ resid,
    float* __restrict__ out, int n4)
{
  const size_t MN = (size_t)S_LEN * D_EMB;
  int stride = gridDim.x * 256;
  for (int e = blockIdx.x * 256 + threadIdx.x; e < n4; e += stride) {
    short4v rv = *(const short4v*)(resid + 4 * (size_t)e);
    int col = (e * 4) % D_EMB;
    float4v bv = *(const float4v*)(bias + col);
    float4v acc;
    #pragma unroll
    for (int j = 0; j < 4; j++) {
      unsigned int u = ((unsigned int)(unsigned short)rv[j]) << 16;
      acc[j] = *reinterpret_cast<float*>(&u) + bv[j];
    }
    #pragma unroll
    for (int s = 0; s < NS; s++) {
      short4v pv = *(const short4v*)(parts + (size_t)s * MN + 4 * (size_t)e);
      #pragma unroll
      for (int j = 0; j < 4; j++) {
        unsigned int u = ((unsigned int)(unsigned short)pv[j]) << 16;
        acc[j] += *reinterpret_cast<float*>(&u);
      }
    }
    *(float4v*)(out + 4 * (size_t)e) = acc;
  }
}

// ---------------- fused split-K(3, bf16) reduce + LayerNorm; x1 stored bf16 ----------------
__global__ __launch_bounds__(256) void reduce_ln_kernel(const __hip_bfloat16* __restrict__ parts,
    const float* __restrict__ bias, const float* __restrict__ resid,
    const float* __restrict__ g, const float* __restrict__ b,
    __hip_bfloat16* __restrict__ x1b, __hip_bfloat16* __restrict__ lnout)
{
  const size_t MN = (size_t)S_LEN * D_EMB;
  int row = blockIdx.x;
  int tid = threadIdx.x;
  float v[3];
  float s = 0.f, sq = 0.f;
  #pragma unroll
  for (int i = 0; i < 3; i++) {
    int col = tid + i * 256;
    size_t idx = (size_t)row * D_EMB + col;
    float a = resid[idx] + bias[col]
            + __bfloat162float(parts[idx])
            + __bfloat162float(parts[idx + MN])
            + __bfloat162float(parts[idx + 2 * MN]);
    x1b[idx] = __float2bfloat16(a);
    v[i] = a;
    s += a;
    sq += a * a;
  }
  #pragma unroll
  for (int off = 32; off >= 1; off >>= 1) {
    s  += __shfl_xor(s, off);
    sq += __shfl_xor(sq, off);
  }
  __shared__ float ss[4], ssq[4];
  if ((tid & 63) == 0) { ss[tid >> 6] = s; ssq[tid >> 6] = sq; }
  __syncthreads();
  s  = ss[0] + ss[1] + ss[2] + ss[3];
  sq = ssq[0] + ssq[1] + ssq[2] + ssq[3];
  float mean = s * (1.0f / D_EMB);
  float var  = sq * (1.0f / D_EMB) - mean * mean;
  float rstd = rsqrtf(var + 1e-5f);
  __hip_bfloat16* orow = lnout + (size_t)row * D_EMB;
  #pragma unroll
  for (int i = 0; i < 3; i++) {
    int col = tid + i * 256;
    orow[col] = __float2bfloat16((v[i] - mean) * rstd * g[col] + b[col]);
  }
}

// ---------------- causal flash attention v13 + setprio (unchanged) ----------------
#define SCL_LOG2E 0.18033688011f
template<bool SPLIT>
__global__ __launch_bounds__(512, 4) void attn_kernel(const __hip_bfloat16* __restrict__ kqv,
                                                      const __hip_bfloat16* __restrict__ vT,
                                                      __hip_bfloat16* __restrict__ y,
                                                      char* __restrict__ partial)
{
  __shared__ __hip_bfloat16 Ksm[2][64 * 64];   // [kv][d] linear, swizzled content
  __shared__ __hip_bfloat16 Vtsm[2][64 * 64];  // [d][kv] linear, swizzled content

  int bid = blockIdx.x;
  int h, gi, c;
  if (SPLIT) {
    int task = (bid >> 3) + (bid & 7) * 60;    // XCD-pinned: xcd = bid&7 owns 60 tasks
    h = task / 40;
    int t = task % 40;                          // heavy groups first
    if      (t < 16) { gi = 15 - (t >> 2);        c = t & 3; }
    else if (t < 28) { gi = 11 - (t - 16) / 3;    c = (t - 16) % 3; }
    else if (t < 36) { gi = 7  - ((t - 28) >> 1); c = (t - 28) & 1; }
    else             { gi = 3  - (t - 36);        c = 0; }
  } else {
    h = bid / 16; gi = 15 - (bid % 16); c = 0;
  }
  int ntile = 4 * gi + 4;
  int kt0 = c << 4;
  int kt1 = SPLIT ? min(kt0 + 16, ntile) : ntile;
  bool direct = SPLIT ? (gi < 4) : true;

  int tid = threadIdx.x;
  int w = tid >> 6, lane = tid & 63, lg = lane >> 4, li = lane & 15;
  int sw = li & 7;
  int qb0 = gi * 256 + w * 16;                  // slab0 base; slab1 = +128

  int ksr  = tid >> 3;
  int kscn = (tid & 7) ^ (ksr & 7);
  const __hip_bfloat16* kSrc0 = kqv + h * HD + (size_t)ksr * DQKV + kscn * 8;
  const __hip_bfloat16* vSrc0 = vT + (size_t)(h * HD + ksr) * S_LEN + kscn * 8;
  const size_t kTileStep = (size_t)64 * DQKV;

  short8v q8[2][2];
  #pragma unroll
  for (int g = 0; g < 2; g++) {
    const __hip_bfloat16* qp = kqv + (size_t)(qb0 + g * 128 + li) * DQKV + D_EMB + h * HD + 8 * lg;
    q8[g][0] = *(const short8v*)(qp);
    q8[g][1] = *(const short8v*)(qp + 32);
  }

  const short4v ones4 = { (short)0x3F80, (short)0x3F80, (short)0x3F80, (short)0x3F80 };
  float4v ol0 = {0.f,0.f,0.f,0.f}, ol1 = {0.f,0.f,0.f,0.f};
  float4v o0[4], o1[4];
  #pragma unroll
  for (int fc = 0; fc < 4; fc++) { float4v z = {0.f,0.f,0.f,0.f}; o0[fc] = z; o1[fc] = z; }

  gload16(kSrc0 + (size_t)kt0 * kTileStep, Ksm[0] + tid * 8);
  gload16(vSrc0 + (size_t)kt0 * 64,        Vtsm[0] + tid * 8);

  for (int kb = kt0; kb < kt1; kb++) {
    int p = kb & 1;
    __syncthreads();
    if (kb + 1 < kt1) {
      gload16(kSrc0 + (size_t)(kb + 1) * kTileStep, Ksm[p ^ 1] + tid * 8);
      gload16(vSrc0 + (size_t)(kb + 1) * 64,        Vtsm[p ^ 1] + tid * 8);
    }

    bool act0 = (kb * 64 <= qb0 + 15);
    bool act1 = (kb * 64 <= qb0 + 128 + 15);
    if (!act1) continue;

    float4v s0[4], s1[4];
    #pragma unroll
    for (int fc = 0; fc < 4; fc++) { float4v z = {0.f,0.f,0.f,0.f}; s0[fc] = z; s1[fc] = z; }
    __builtin_amdgcn_s_setprio(1);
    #pragma unroll
    for (int kk = 0; kk < 2; kk++) {
      #pragma unroll
      for (int fc = 0; fc < 4; fc++) {
        int ch = ((kk << 2) | lg) ^ sw;
        short8v kf = *(const short8v*)(Ksm[p] + (fc * 16 + li) * 64 + ch * 8);
        s0[fc] = __builtin_amdgcn_mfma_f32_16x16x32_bf16(kf, q8[0][kk], s0[fc], 0, 0, 0);
        s1[fc] = __builtin_amdgcn_mfma_f32_16x16x32_bf16(kf, q8[1][kk], s1[fc], 0, 0, 0);
      }
    }
    __builtin_amdgcn_s_setprio(0);

    if (act0) {
      bool needmask = (kb * 64 + 63 > qb0);
      if (needmask) {
        #pragma unroll
        for (int fc = 0; fc < 4; fc++) {
          #pragma unroll
          for (int rr = 0; rr < 4; rr++) {
            float pv = fast_exp2(s0[fc][rr] * SCL_LOG2E);
            if ((kb * 64 + fc * 16 + 4 * lg + rr) > (qb0 + li)) pv = 0.f;
            s0[fc][rr] = pv;
          }
        }
      } else {
        #pragma unroll
        for (int fc = 0; fc < 4; fc++) {
          #pragma unroll
          for (int rr = 0; rr < 4; rr++)
            s0[fc][rr] = fast_exp2(s0[fc][rr] * SCL_LOG2E);
        }
      }
    }

    {
      int qb1 = qb0 + 128;
      bool needmask = (kb * 64 + 63 > qb1);
      if (needmask) {
        #pragma unroll
        for (int fc = 0; fc < 4; fc++) {
          #pragma unroll
          for (int rr = 0; rr < 4; rr++) {
            float pv = fast_exp2(s1[fc][rr] * SCL_LOG2E);
            if ((kb * 64 + fc * 16 + 4 * lg + rr) > (qb1 + li)) pv = 0.f;
            s1[fc][rr] = pv;
          }
        }
      } else {
        #pragma unroll
        for (int fc = 0; fc < 4; fc++) {
          #pragma unroll
          for (int rr = 0; rr < 4; rr++)
            s1[fc][rr] = fast_exp2(s1[fc][rr] * SCL_LOG2E);
        }
      }
    }

    __builtin_amdgcn_s_setprio(1);
    if (act0) {
      #pragma unroll
      for (int kk = 0; kk < 4; kk++) {
        short4v pb0, pb1;
        #pragma unroll
        for (int rr = 0; rr < 4; rr++) { pb0[rr] = bf16bits(s0[kk][rr]); pb1[rr] = bf16bits(s1[kk][rr]); }
        ol0 = mfma16(ones4, pb0, ol0);
        ol1 = mfma16(ones4, pb1, ol1);
        int c2 = (kk << 1) | (lg >> 1);
        #pragma unroll
        for (int fc = 0; fc < 4; fc++) {
          short4v vf = *(const short4v*)(Vtsm[p] + (fc * 16 + li) * 64 + ((c2 ^ sw) << 3) + 4 * (lg & 1));
          o0[fc] = mfma16(vf, pb0, o0[fc]);
          o1[fc] = mfma16(vf, pb1, o1[fc]);
        }
      }
    } else {
      #pragma unroll
      for (int kk = 0; kk < 4; kk++) {
        short4v pb1;
        #pragma unroll
        for (int rr = 0; rr < 4; rr++) pb1[rr] = bf16bits(s1[kk][rr]);
        ol1 = mfma16(ones4, pb1, ol1);
        int c2 = (kk << 1) | (lg >> 1);
        #pragma unroll
        for (int fc = 0; fc < 4; fc++) {
          short4v vf = *(const short4v*)(Vtsm[p] + (fc * 16 + li) * 64 + ((c2 ^ sw) << 3) + 4 * (lg & 1));
          o1[fc] = mfma16(vf, pb1, o1[fc]);
        }
      }
    }
    __builtin_amdgcn_s_setprio(0);
  }

  if (direct) {
    float inv0 = 1.0f / ol0[0], inv1 = 1.0f / ol1[0];
    int q0 = qb0 + li;
    #pragma unroll
    for (int fc = 0; fc < 4; fc++) {
      short4v ov0, ov1;
      #pragma unroll
      for (int rr = 0; rr < 4; rr++) { ov0[rr] = bf16bits(o0[fc][rr] * inv0); ov1[rr] = bf16bits(o1[fc][rr] * inv1); }
      *reinterpret_cast<short4v*>(y + (size_t)q0 * D_EMB + h * HD + fc * 16 + 4 * lg) = ov0;
      *reinterpret_cast<short4v*>(y + (size_t)(q0 + 128) * D_EMB + h * HD + fc * 16 + 4 * lg) = ov1;
    }
  } else {
    int offg = (gi < 8) ? (gi - 4) * 2 : (gi < 12) ? 8 + (gi - 8) * 3 : 20 + (gi - 12) * 4;
    char* slot = partial + (size_t)(h * 36 + offg + c) * 33792;
    int q = (w & 3) * 16 + li;
    #pragma unroll
    for (int g = 0; g < 2; g++) {
      char* ps = slot + (size_t)(g * 2 + (w >> 2)) * 8448;
      __hip_bfloat16* pO = (__hip_bfloat16*)ps;
      float* pL = (float*)(ps + 8192);
      #pragma unroll
      for (int fc = 0; fc < 4; fc++) {
        #pragma unroll
        for (int rr = 0; rr < 4; rr++) {
          float val = g ? o1[fc][rr] : o0[fc][rr];
          pO[(fc * 16 + 4 * lg + rr) * 64 + q] = __float2bfloat16(val);
        }
      }
      if (lg == 0) pL[q] = g ? ol1[0] : ol0[0];
    }
  }
}

// ---------------- attn combine: plain sum of <=4 kv-chunks per (h, qb>=16) slab ----------------
__global__ __launch_bounds__(256) void attn_combine_kernel(const char* __restrict__ partial,
                                                           __hip_bfloat16* __restrict__ y)
{
  int task = blockIdx.x;            // 576 = 12 * 48
  int h  = task / 48;
  int qb = 16 + task % 48;
  int gi = qb >> 2, slab = qb & 3;
  int nch = (gi >> 2) + 1;
  int offg = (gi < 8) ? (gi - 4) * 2 : (gi < 12) ? 8 + (gi - 8) * 3 : 20 + (gi - 12) * 4;
  const char* base = partial + (size_t)(h * 36 + offg) * 33792 + (size_t)slab * 8448;
  int wv = threadIdx.x >> 6;
  int lane = threadIdx.x & 63;

  float L = 0.f;
  float acc[16];
  #pragma unroll
  for (int j = 0; j < 16; j++) acc[j] = 0.f;
  #pragma unroll
  for (int c = 0; c < 4; c++) {
    if (c < nch) {
      const char* cb = base + (size_t)c * 33792;
      L += ((const float*)(cb + 8192))[lane];
      const __hip_bfloat16* O = (const __hip_bfloat16*)cb;
      #pragma unroll
      for (int j = 0; j < 16; j++)
        acc[j] += __bfloat162float(O[(wv * 16 + j) * 64 + lane]);
    }
  }
  float inv = 1.0f / L;
  __hip_bfloat16* yp = y + (size_t)(qb * 64 + lane) * D_EMB + h * HD + wv * 16;
  short8v a0, a1;
  #pragma unroll
  for (int j = 0; j < 8; j++) a0[j] = bf16bits(acc[j] * inv);
  #pragma unroll
  for (int j = 0; j < 8; j++) a1[j] = bf16bits(acc[8 + j] * inv);
  *reinterpret_cast<short8v*>(yp)     = a0;
  *reinterpret_cast<short8v*>(yp + 8) = a1;
}

// ---------------- launch ----------------
extern "C" void kernel_launch(void* const* d_in, const int* in_sizes, int n_in,
                              void* d_out, int out_size, void* d_ws, size_t ws_size,
                              hipStream_t stream)
{
  const float* x      = (const float*)d_in[0];
  const float* w_qkv  = (const float*)d_in[1];
  const float* b_qkv  = (const float*)d_in[2];
  const float* w_proj = (const float*)d_in[3];
  const float* b_proj = (const float*)d_in[4];
  const float* w_fc1  = (const float*)d_in[5];
  const float* b_fc1  = (const float*)d_in[6];
  const float* w_fc2  = (const float*)d_in[7];
  const float* b_fc2  = (const float*)d_in[8];
  const float* ln1_g  = (const float*)d_in[9];
  const float* ln1_b  = (const float*)d_in[10];
  const float* ln2_g  = (const float*)d_in[11];
  const float* ln2_b  = (const float*)d_in[12];

  char* ws = (char*)d_ws;
  size_t off = 0;
  __hip_bfloat16* wqkvT = (__hip_bfloat16*)(ws + off); off += (size_t)DQKV * D_EMB * 2;
  __hip_bfloat16* wprojT= (__hip_bfloat16*)(ws + off); off += (size_t)D_EMB * D_EMB * 2;
  __hip_bfloat16* wfc1T = (__hip_bfloat16*)(ws + off); off += (size_t)DFF * D_EMB * 2;
  __hip_bfloat16* wfc2T = (__hip_bfloat16*)(ws + off); off += (size_t)D_EMB * DFF * 2;
  __hip_bfloat16* lnbuf = (__hip_bfloat16*)(ws + off); off += (size_t)S_LEN * D_EMB * 2;
  __hip_bfloat16* kqv   = (__hip_bfloat16*)(ws + off);
  __hip_bfloat16* hbuf  = kqv;                         off += (size_t)S_LEN * DQKV * 2;
  __hip_bfloat16* ybuf  = (__hip_bfloat16*)(ws + off); off += (size_t)S_LEN * D_EMB * 2;
  __hip_bfloat16* vTbuf = (__hip_bfloat16*)(ws + off); off += (size_t)S_LEN * D_EMB * 2;
  char*           x1mem = ws + off;                    off += (size_t)S_LEN * D_EMB * 4;
  __hip_bfloat16* x1b   = (__hip_bfloat16*)x1mem;      // bf16 view (split path)
  float*          x1f   = (float*)x1mem;               // fp32 view (fallback path)
  char*           part  = ws + off;                    // split-K bf16 planes; attn partials alias
  size_t needSplit = off + (size_t)3 * S_LEN * D_EMB * 2;   // 3 bf16 planes (18.9 MB)
  size_t needAttn  = off + (size_t)432 * 33792;             // 14.6 MB
  bool splitk  = (ws_size >= needSplit);
  bool attnSpl = (ws_size >= needAttn);
  const int MN4 = S_LEN * D_EMB / 4;
  (void)in_sizes; (void)n_in; (void)out_size;

  // merged weight transposes + ln1 (independent work, one launch)
  transpose_ln_kernel<<<dim3(6912 + S_LEN), dim3(256), 0, stream>>>(
      w_qkv, w_proj, w_fc1, w_fc2, wqkvT, wprojT, wfc1T, wfc2T,
      x, ln1_g, ln1_b, lnbuf);

  // qkv GEMM also emits vT (EPI 4)
  gemm_kernel<4><<<dim3((DQKV/128)*(S_LEN/128)), dim3(256), 0, stream>>>(
      lnbuf, wqkvT, b_qkv, nullptr, kqv, vTbuf, S_LEN, DQKV, D_EMB, D_EMB);

  if (attnSpl) {
    attn_kernel<true><<<dim3(480), dim3(512), 0, stream>>>(kqv, vTbuf, ybuf, part);
    attn_combine_kernel<<<dim3(576), dim3(256), 0, stream>>>(part, ybuf);
  } else {
    attn_kernel<false><<<dim3(192), dim3(512), 0, stream>>>(kqv, vTbuf, ybuf, part);
  }

  if (splitk) {
    // proj split-K x3 (bf16 partials), then fused reduce+LN (writes bf16 x1 and lnbuf)
    gemm_kernel<3><<<dim3((D_EMB/128)*(S_LEN/128)*3), dim3(256), 0, stream>>>(
        ybuf, wprojT, nullptr, nullptr, part, nullptr, S_LEN, D_EMB, D_EMB, D_EMB/3);
    reduce_ln_kernel<<<dim3(S_LEN), dim3(256), 0, stream>>>(
        (const __hip_bfloat16*)part, b_proj, x, ln2_g, ln2_b, x1b, lnbuf);
  } else {
    gemm_kernel<2><<<dim3((D_EMB/128)*(S_LEN/128)), dim3(256), 0, stream>>>(
        ybuf, wprojT, b_proj, x, x1f, nullptr, S_LEN, D_EMB, D_EMB, D_EMB);
    ln_kernel<<<dim3(S_LEN), dim3(256), 0, stream>>>(x1f, ln2_g, ln2_b, lnbuf);
  }

  gemm_kernel<1><<<dim3((DFF/128)*(S_LEN/128)), dim3(256), 0, stream>>>(
      lnbuf, wfc1T, b_fc1, nullptr, hbuf, nullptr, S_LEN, DFF, D_EMB, D_EMB);

  if (splitk) {
    // fc2 split-K x3 (bf16 partials, 576 blocks), reduce with bf16 residual x1
    gemm_kernel<3><<<dim3((D_EMB/128)*(S_LEN/128)*3), dim3(256), 0, stream>>>(
        hbuf, wfc2T, nullptr, nullptr, part, nullptr, S_LEN, D_EMB, DFF, DFF/3);
    reduce_kernel<3><<<dim3(1024), dim3(256), 0, stream>>>(
        (const __hip_bfloat16*)part, b_fc2, x1b, (float*)d_out, MN4);
  } else {
    // fallback: fp32 x1 residual folded via EPI2 (resid = x1f)
    gemm_kernel<2><<<dim3((D_EMB/128)*(S_LEN/128)), dim3(256), 0, stream>>>(
        hbuf, wfc2T, b_fc2, x1f, (float*)d_out, nullptr, S_LEN, D_EMB, DFF, DFF);
  }
}